// Round 4
// baseline (2551.583 us; speedup 1.0000x reference)
//
#include <hip/hip_runtime.h>
#include <hip/hip_cooperative_groups.h>

namespace cg = cooperative_groups;

#define GBS 256   // grid blocks
#define T   256   // threads per block
#define RC  130816  // 511*256

__device__ __forceinline__ float sigmf(float x){ return 1.0f/(1.0f+__expf(-x)); }
__device__ __forceinline__ float tanhfast(float x){
  x = fminf(fmaxf(x, -15.0f), 15.0f);
  float e = __expf(2.0f*x);
  return (e-1.0f)/(e+1.0f);
}

struct KParams {
  const int *l_idx, *r_idx;
  const float *emb, *W_ioux, *b_ioux, *W_iouh, *b_iouh, *W_fh, *b_fh;
  const float *Wa, *W_attnh, *b_attnh, *W_wh, *b_wh, *W_wp, *b_wp;
  float* out;
  float* ws;
};

// ---------------------------------------------------------------------------
// Gate-dot phase: for rows [0,Nc) of both passes, compute
//   iou[p][n][col] (768 cols, WiT) and fg[p][n][0/1][col] (WfT) dots.
// Items: iou (p, rowchunk8, colchunk of 256)*  + f (p, rowchunk8).
// ---------------------------------------------------------------------------
__device__ void phase_gates(int bid, int tid, float* sm,
                            const float* hmat0, const float* hmat1,
                            int Nc, int offPrev,
                            const float* WiT, const float* WfT,
                            float* iou, float* fg)
{
  int rcn = (Nc+7)>>3;
  int ni = 2*rcn*3, nt = ni + 2*rcn;
  for (int it = bid; it < nt; it += GBS){
    __syncthreads();
    if (it < ni){
      int p = it/(rcn*3); int rem = it - p*rcn*3; int rc = rem/3, cc = rem - rc*3;
      int r0 = rc*8, rcount = min(8, Nc - r0);
      const float* hmat = p ? hmat1 : hmat0;
      for (int j = tid; j < rcount*256; j += T){
        int rr = j>>8, d = j&255;
        const float* hr = hmat + ((size_t)(offPrev + 2*(r0+rr)))*256;
        sm[rr*256+d] = hr[d] + hr[256+d];
      }
      __syncthreads();
      int col = cc*256 + tid;
      float acc[8] = {0,0,0,0,0,0,0,0};
      #pragma unroll 4
      for (int d = 0; d < 256; ++d){
        float w = WiT[(size_t)d*768 + col];
        #pragma unroll
        for (int rr = 0; rr < 8; ++rr) acc[rr] += sm[rr*256+d]*w;
      }
      #pragma unroll
      for (int rr = 0; rr < 8; ++rr)
        if (rr < rcount) iou[((size_t)(p*256 + r0+rr))*768 + col] = acc[rr];
    } else {
      int it2 = it - ni; int p = it2/rcn, rc = it2 - p*rcn;
      int r0 = rc*8, rcount = min(8, Nc - r0);
      const float* hmat = p ? hmat1 : hmat0;
      for (int j = tid; j < rcount*256; j += T){
        int rr = j>>8, d = j&255;
        const float* hr = hmat + ((size_t)(offPrev + 2*(r0+rr)))*256;
        sm[rr*256+d] = hr[d];
        sm[2048 + rr*256+d] = hr[256+d];
      }
      __syncthreads();
      float a0[8] = {0,0,0,0,0,0,0,0}, a1[8] = {0,0,0,0,0,0,0,0};
      #pragma unroll 2
      for (int d = 0; d < 256; ++d){
        float w = WfT[(size_t)d*256 + tid];
        #pragma unroll
        for (int rr = 0; rr < 8; ++rr){
          a0[rr] += sm[rr*256+d]*w;
          a1[rr] += sm[2048 + rr*256+d]*w;
        }
      }
      #pragma unroll
      for (int rr = 0; rr < 8; ++rr)
        if (rr < rcount){
          fg[((size_t)(p*256 + r0+rr))*512 + tid]       = a0[rr];
          fg[((size_t)(p*256 + r0+rr))*512 + 256 + tid] = a1[rr];
        }
    }
  }
}

// ---------------------------------------------------------------------------
// Score phase: e[p][n][m] = exp( sum_d wa[d]*tanh(hp[p][n][d] + proj[p][m][d]) )
// proj row-major per m -> float4 loads per thread. Items: (p, n, m-chunk of 256).
// ---------------------------------------------------------------------------
__device__ void phase_scores(int bid, int tid, float* sm, int Nc,
                             const float* hp, const float* proj,
                             const float* Wa, float* sc)
{
  int items = 2*Nc*2;
  for (int it = bid; it < items; it += GBS){
    __syncthreads();
    int p = it/(Nc*2); int rem = it - p*Nc*2; int n = rem>>1, ch = rem&1;
    sm[tid]       = hp[((size_t)(p*256 + n))*256 + tid];
    sm[256 + tid] = Wa[tid];
    __syncthreads();
    int m = ch*256 + tid;
    if (m < 511){
      const float4* pr = (const float4*)(proj + ((size_t)p*511 + m)*256);
      float s = 0.f;
      #pragma unroll 8
      for (int d4 = 0; d4 < 64; ++d4){
        float4 q = pr[d4];
        s += sm[256+4*d4+0]*tanhfast(sm[4*d4+0] + q.x);
        s += sm[256+4*d4+1]*tanhfast(sm[4*d4+1] + q.y);
        s += sm[256+4*d4+2]*tanhfast(sm[4*d4+2] + q.z);
        s += sm[256+4*d4+3]*tanhfast(sm[4*d4+3] + q.w);
      }
      sc[((size_t)(p*256 + n))*512 + m] = __expf(s);
    } else {
      sc[((size_t)(p*256 + n))*512 + 511] = 0.f;
    }
  }
}

// ---------------------------------------------------------------------------
// Weighted-sum + finish phase:
//   h_out[p][n][t] = colsum[p][t] - (sum_m e[m]*mat[p][m][t])/(sum_m e[m]) + h_pre[p][n][t]
// Items: (p, rowchunk of 4). Writes hCD[p][offCur+n].
// ---------------------------------------------------------------------------
__device__ void phase_wsum(int bid, int tid, float* sm, int Nc, int offCur,
                           const float* sc, const float* matAB, const float* cs,
                           const float* hstage, float* hCD)
{
  int rc4n = (Nc+3)>>2;
  int items = 2*rc4n;
  for (int it = bid; it < items; it += GBS){
    __syncthreads();
    int p = it/rc4n, rc = it - p*rc4n;
    int r0 = rc*4, rcount = min(4, Nc - r0);
    for (int j = tid; j < rcount*512; j += T){
      int rr = j>>9, m = j&511;
      sm[rr*512+m] = sc[((size_t)(p*256 + r0+rr))*512 + m];
    }
    __syncthreads();
    for (int rr = 0; rr < 4; ++rr){
      float v = (rr < rcount) ? sm[rr*512+tid] + sm[rr*512+256+tid] : 0.f;
      sm[2048+tid] = v; __syncthreads();
      for (int off = 128; off > 0; off >>= 1){
        if (tid < off) sm[2048+tid] += sm[2048+tid+off];
        __syncthreads();
      }
      if (tid == 0) sm[2560+rr] = sm[2048];
      __syncthreads();
    }
    const float* matp = matAB + (size_t)p*RC;
    float acc[4] = {0,0,0,0};
    #pragma unroll 8
    for (int m = 0; m < 511; ++m){
      float mv = matp[(size_t)m*256 + tid];
      #pragma unroll
      for (int rr = 0; rr < 4; ++rr) acc[rr] += sm[rr*512+m]*mv;
    }
    float csv = cs[p*256 + tid];
    #pragma unroll
    for (int rr = 0; rr < 4; ++rr)
      if (rr < rcount){
        int n = r0 + rr;
        float inv = 1.0f/sm[2560+rr];
        float hv = hstage[((size_t)(p*256 + n))*256 + tid];
        hCD[(size_t)p*RC + ((size_t)(offCur + n))*256 + tid] = csv - acc[rr]*inv + hv;
      }
  }
}

__global__ void __launch_bounds__(256) coop_kernel(KParams P)
{
  cg::grid_group gg = cg::this_grid();
  const int bid = blockIdx.x, tid = threadIdx.x;
  __shared__ float sm[4096];  // 16 KiB scratch, carved per phase

  // ---- workspace carve ----
  float* cmatAB = P.ws;               // 2*RC
  float* cmatCD = cmatAB + 2*RC;      // 2*RC
  float* matAB  = cmatCD + 2*RC;      // 2*RC   (matL, matR)
  float* hCD    = matAB  + 2*RC;      // 2*RC
  float* proj   = hCD    + 2*RC;      // 2*RC   ([p][m][256], m-major)
  float* sc     = proj   + 2*RC;      // 2*256*512
  float* iou    = sc     + 262144;    // 2*256*768
  float* fg     = iou    + 393216;    // 2*256*512
  float* hp     = fg     + 262144;    // 2*256*256
  float* hstage = hp     + 131072;    // 2*256*256
  float* colpart= hstage + 131072;    // 2*8*256
  float* cs     = colpart+ 4096;      // 2*256
  float* WxT    = cs     + 512;       // 300*768
  float* WiT    = WxT    + 230400;    // 256*768
  float* WfT    = WiT    + 196608;    // 256*256
  float* W1T    = WfT    + 65536;     // 256*256
  float* W2T    = W1T    + 65536;     // 256*256
  float* WhT    = W2T    + 65536;     // 512*128

  const int offs[9] = {0, 256, 384, 448, 480, 496, 504, 508, 510};
  const int gs = GBS*T;
  const int g0 = bid*T + tid;

  // ================= PREP: weight transposes =================
  for (int i = g0; i < 768*300; i += gs){ int r = i/300, d = i - r*300; WxT[(size_t)d*768 + r] = P.W_ioux[i]; }
  for (int i = g0; i < 768*256; i += gs){ int r = i>>8, d = i&255; WiT[(size_t)d*768 + r] = P.W_iouh[i]; }
  for (int i = g0; i < 256*256; i += gs){ int r = i>>8, d = i&255; WfT[(size_t)d*256 + r] = P.W_fh[i]; }
  for (int i = g0; i < 256*512; i += gs){
    int r = i>>9, d = i&511; float v = P.W_attnh[i];
    if (d < 256) W1T[(size_t)d*256 + r] = v; else W2T[(size_t)(d-256)*256 + r] = v;
  }
  for (int i = g0; i < 128*512; i += gs){ int r = i>>9, d = i&511; WhT[(size_t)d*128 + r] = P.W_wh[i]; }
  gg.sync();

  // ================= INIT P1: x @ W_ioux^T dots =================
  // items: (rowchunk8 over 512 global rows [A:0..255, B:256..511], colchunk of 256)
  for (int it = bid; it < 64*3; it += GBS){
    __syncthreads();
    int rc = it/3, cc = it - rc*3;
    int r0 = rc*8;                     // 8 rows, same pass (256%8==0)
    int p = r0>>8, n0 = r0&255;
    for (int j = tid; j < 8*300; j += T){
      int rr = j/300, d = j - rr*300;
      int n = n0 + rr;
      int row = p ? P.r_idx[n] : P.l_idx[n];
      sm[rr*304 + d] = P.emb[(size_t)row*300 + d];
    }
    __syncthreads();
    int col = cc*256 + tid;
    float acc[8] = {0,0,0,0,0,0,0,0};
    #pragma unroll 4
    for (int d = 0; d < 300; ++d){
      float w = WxT[(size_t)d*768 + col];
      #pragma unroll
      for (int rr = 0; rr < 8; ++rr) acc[rr] += sm[rr*304+d]*w;
    }
    #pragma unroll
    for (int rr = 0; rr < 8; ++rr) iou[((size_t)(p*256 + n0+rr))*768 + col] = acc[rr];
  }
  gg.sync();

  // ================= INIT P2: gates -> c0,h0 =================
  for (int idx = g0; idx < 2*256*256; idx += gs){
    int p = idx>>16, rem = idx&65535, n = rem>>8, t = rem&255;
    size_t gb = ((size_t)(p*256 + n))*768;
    float i_ = sigmf(iou[gb+t]       + P.b_ioux[t]     + P.b_iouh[t]);
    float o_ = sigmf(iou[gb+256+t]   + P.b_ioux[256+t] + P.b_iouh[256+t]);
    float u_ = tanhfast(iou[gb+512+t]+ P.b_ioux[512+t] + P.b_iouh[512+t]);
    float c = i_*u_;
    float h = o_*tanhfast(c);
    cmatAB[(size_t)p*RC + (size_t)n*256 + t] = c;
    matAB [(size_t)p*RC + (size_t)n*256 + t] = h;
  }
  gg.sync();

  // ================= A/B tree levels (no attention) =================
  for (int lvl = 1; lvl <= 8; ++lvl){
    int Nc = 256>>lvl, offPrev = offs[lvl-1], offCur = offs[lvl];
    phase_gates(bid, tid, sm, matAB, matAB + RC, Nc, offPrev, WiT, WfT, iou, fg);
    gg.sync();
    for (int idx = g0; idx < 2*Nc*256; idx += gs){
      int p = idx/(Nc<<8); int rem = idx - p*(Nc<<8); int n = rem>>8, t = rem&255;
      size_t gb = ((size_t)(p*256 + n))*768;
      size_t fb = ((size_t)(p*256 + n))*512;
      float* cm = cmatAB + (size_t)p*RC;
      float i_ = sigmf(iou[gb+t]        + P.b_iouh[t]);
      float o_ = sigmf(iou[gb+256+t]    + P.b_iouh[256+t]);
      float u_ = tanhfast(iou[gb+512+t] + P.b_iouh[512+t]);
      float bf = P.b_fh[t];
      float f0 = sigmf(fg[fb+t] + bf), f1 = sigmf(fg[fb+256+t] + bf);
      float c0 = cm[((size_t)(offPrev+2*n))*256 + t];
      float c1 = cm[((size_t)(offPrev+2*n+1))*256 + t];
      float c = i_*u_ + f0*c0 + f1*c1;
      float h = o_*tanhfast(c);
      cm[((size_t)(offCur+n))*256 + t] = c;
      matAB[(size_t)p*RC + ((size_t)(offCur+n))*256 + t] = h;
    }
    gg.sync();
  }

  // ================= PROJ (+ colsum partials) =================
  // proj items: (p, rowchunk8 over 511); colpart items: (p, group of 64 rows)
  for (int it = bid; it < 128 + 16; it += GBS){
    __syncthreads();
    if (it < 128){
      int p = it>>6, rc = it&63;
      int r0 = rc*8, rcount = min(8, 511 - r0);
      const float* matp = matAB + (size_t)p*RC;
      for (int j = tid; j < rcount*256; j += T){
        int rr = j>>8, d = j&255;
        sm[rr*256+d] = matp[((size_t)(r0+rr))*256 + d];
      }
      __syncthreads();
      float acc[8] = {0,0,0,0,0,0,0,0};
      #pragma unroll 4
      for (int e = 0; e < 256; ++e){
        float w = W2T[(size_t)e*256 + tid];
        #pragma unroll
        for (int rr = 0; rr < 8; ++rr) acc[rr] += sm[rr*256+e]*w;
      }
      float ba = P.b_attnh[tid];
      #pragma unroll
      for (int rr = 0; rr < 8; ++rr)
        if (rr < rcount) proj[((size_t)p*511 + r0+rr)*256 + tid] = acc[rr] + ba;
    } else {
      int it2 = it - 128; int p = it2>>3, g = it2&7;
      int m0 = g*64, mcnt = min(64, 511 - m0);
      const float* matp = matAB + (size_t)p*RC;
      float s = 0.f;
      #pragma unroll 8
      for (int m = 0; m < mcnt; ++m) s += matp[((size_t)(m0+m))*256 + tid];
      colpart[((size_t)(p*8 + g))*256 + tid] = s;
    }
  }
  gg.sync();

  // ================= ATT-INIT A: hp dots + extras =================
  // hp items: (p=C/D, rowchunk8 over 256 rows); h source: C<-matR, D<-matL
  for (int it = bid; it < 64; it += GBS){
    __syncthreads();
    int p = it>>5, rc = it&31;
    int r0 = rc*8;
    const float* hsrc = matAB + (size_t)(1-p)*RC;
    for (int j = tid; j < 8*256; j += T){
      int rr = j>>8, d = j&255;
      float v = hsrc[((size_t)(r0+rr))*256 + d];
      sm[rr*256+d] = v;
      hstage[((size_t)(p*256 + r0+rr))*256 + d] = v;
    }
    __syncthreads();
    float acc[8] = {0,0,0,0,0,0,0,0};
    #pragma unroll 4
    for (int e = 0; e < 256; ++e){
      float w = W1T[(size_t)e*256 + tid];
      #pragma unroll
      for (int rr = 0; rr < 8; ++rr) acc[rr] += sm[rr*256+e]*w;
    }
    #pragma unroll
    for (int rr = 0; rr < 8; ++rr) hp[((size_t)(p*256 + r0+rr))*256 + tid] = acc[rr];
  }
  // extras: colsum reduce + c-copy (C<-B, D<-A)
  for (int idx = g0; idx < 512; idx += gs){
    int p = idx>>8, t = idx&255;
    float s = 0.f;
    #pragma unroll
    for (int g = 0; g < 8; ++g) s += colpart[((size_t)(p*8 + g))*256 + t];
    cs[p*256 + t] = s;
  }
  for (int idx = g0; idx < 2*256*256; idx += gs){
    int p = idx>>16, rem = idx&65535, n = rem>>8, t = rem&255;
    cmatCD[(size_t)p*RC + (size_t)n*256 + t] = cmatAB[(size_t)(1-p)*RC + (size_t)n*256 + t];
  }
  gg.sync();

  // ================= ATT-INIT B: scores =================
  phase_scores(bid, tid, sm, 256, hp, proj, P.Wa, sc);
  gg.sync();

  // ================= ATT-INIT C: weighted sum -> hCD rows [0,256) ============
  phase_wsum(bid, tid, sm, 256, 0, sc, matAB, cs, hstage, hCD);
  gg.sync();

  // ================= C/D tree levels (fused attention) =================
  for (int lvl = 1; lvl <= 8; ++lvl){
    int Nc = 256>>lvl, offPrev = offs[lvl-1], offCur = offs[lvl];
    // P1: gate dots
    phase_gates(bid, tid, sm, hCD, hCD + RC, Nc, offPrev, WiT, WfT, iou, fg);
    gg.sync();
    // P2+3: c,h elementwise then hp dots (block per (p, rowchunk8))
    {
      int rcn = (Nc+7)>>3;
      for (int it = bid; it < 2*rcn; it += GBS){
        __syncthreads();
        int p = it/rcn, rc = it - p*rcn;
        int r0 = rc*8, rcount = min(8, Nc - r0);
        float* cm = cmatCD + (size_t)p*RC;
        for (int j = tid; j < rcount*256; j += T){
          int rr = j>>8, t = j&255; int n = r0 + rr;
          size_t gb = ((size_t)(p*256 + n))*768;
          size_t fb = ((size_t)(p*256 + n))*512;
          float i_ = sigmf(iou[gb+t]        + P.b_iouh[t]);
          float o_ = sigmf(iou[gb+256+t]    + P.b_iouh[256+t]);
          float u_ = tanhfast(iou[gb+512+t] + P.b_iouh[512+t]);
          float bf = P.b_fh[t];
          float f0 = sigmf(fg[fb+t] + bf), f1 = sigmf(fg[fb+256+t] + bf);
          float c0 = cm[((size_t)(offPrev+2*n))*256 + t];
          float c1 = cm[((size_t)(offPrev+2*n+1))*256 + t];
          float c = i_*u_ + f0*c0 + f1*c1;
          float h = o_*tanhfast(c);
          cm[((size_t)(offCur+n))*256 + t] = c;
          hstage[((size_t)(p*256 + n))*256 + t] = h;
          sm[rr*256 + t] = h;
        }
        __syncthreads();
        float acc[8] = {0,0,0,0,0,0,0,0};
        #pragma unroll 4
        for (int e = 0; e < 256; ++e){
          float w = W1T[(size_t)e*256 + tid];
          #pragma unroll
          for (int rr = 0; rr < 8; ++rr) acc[rr] += sm[rr*256+e]*w;
        }
        #pragma unroll
        for (int rr = 0; rr < 8; ++rr)
          if (rr < rcount) hp[((size_t)(p*256 + r0+rr))*256 + tid] = acc[rr];
      }
    }
    gg.sync();
    // P4: scores
    phase_scores(bid, tid, sm, Nc, hp, proj, P.Wa, sc);
    gg.sync();
    // P5: weighted sum + finish -> hCD[offCur..]
    phase_wsum(bid, tid, sm, Nc, offCur, sc, matAB, cs, hstage, hCD);
    gg.sync();
  }

  // ================= HEAD (block 0) =================
  if (bid == 0){
    __shared__ float v[512], og[128], lg[8];
    const float* lh1 = matAB + ((size_t)510)*256;            // pass A final
    const float* rh2 = matAB + RC + ((size_t)510)*256;       // pass B final
    const float* rh1 = hCD   + ((size_t)510)*256;            // pass C final
    const float* lh2 = hCD   + RC + ((size_t)510)*256;       // pass D final
    int t = tid;
    if (t < 256){
      float lh = tanhfast(lh1[t] + lh2[t]);
      float rh = tanhfast(rh1[t] + rh2[t]);
      v[t] = lh*rh;
      v[256+t] = fabsf(lh - rh);
    }
    __syncthreads();
    if (t < 128){
      float a = P.b_wh[t];
      #pragma unroll 4
      for (int e = 0; e < 512; ++e) a += v[e]*WhT[(size_t)e*128 + t];
      og[t] = sigmf(a);
    }
    __syncthreads();
    if (t < 5){
      float a2 = P.b_wp[t];
      for (int j = 0; j < 128; ++j) a2 += og[j]*P.W_wp[(size_t)t*128 + j];
      lg[t] = a2;
    }
    __syncthreads();
    if (t == 0){
      float M = -1e30f;
      for (int c = 0; c < 5; ++c) M = fmaxf(M, lg[c]);
      float S = 0.f;
      for (int c = 0; c < 5; ++c) S += __expf(lg[c] - M);
      float L = logf(S);
      for (int c = 0; c < 5; ++c) P.out[c] = lg[c] - M - L;
    }
  }
}

extern "C" void kernel_launch(void* const* d_in, const int* in_sizes, int n_in,
                              void* d_out, int out_size, void* d_ws, size_t ws_size,
                              hipStream_t stream)
{
  KParams prm;
  prm.l_idx   = (const int*)  d_in[0];
  prm.r_idx   = (const int*)  d_in[1];
  prm.emb     = (const float*)d_in[2];
  prm.W_ioux  = (const float*)d_in[3];
  prm.b_ioux  = (const float*)d_in[4];
  prm.W_iouh  = (const float*)d_in[5];
  prm.b_iouh  = (const float*)d_in[6];
  // d_in[7]=W_fx, d_in[8]=b_fx unused
  prm.W_fh    = (const float*)d_in[9];
  prm.b_fh    = (const float*)d_in[10];
  prm.Wa      = (const float*)d_in[11];
  prm.W_attnh = (const float*)d_in[12];
  prm.b_attnh = (const float*)d_in[13];
  prm.W_wh    = (const float*)d_in[14];
  prm.b_wh    = (const float*)d_in[15];
  prm.W_wp    = (const float*)d_in[16];
  prm.b_wp    = (const float*)d_in[17];
  prm.out     = (float*)d_out;
  prm.ws      = (float*)d_ws;

  void* args[] = { &prm };
  hipLaunchCooperativeKernel((const void*)coop_kernel, dim3(GBS), dim3(T),
                             args, 0, stream);
}

// Round 5
// 1142.916 us; speedup vs baseline: 2.2325x; 2.2325x over previous
//
#include <hip/hip_runtime.h>

#define RC 130816   // 511*256
#define MT 512      // matT m-stride (511 padded to 512)

__device__ __forceinline__ float sigmf(float x){ return 1.0f/(1.0f+__expf(-x)); }
__device__ __forceinline__ float tanhfast(float x){
  x = fminf(fmaxf(x,-15.f),15.f);
  float e = __expf(2.f*x);
  return (e-1.f)/(e+1.f);
}

// ---------------------------------------------------------------------------
// Init: 128 blocks x 256 thr; block = (pass p, 4 rows). Per-thread contiguous
// float4 weight streams over W_ioux rows t, t+256, t+512; x tile in LDS
// interleaved [d][rr] so inner reads are wave-uniform broadcasts.
// ---------------------------------------------------------------------------
__global__ void __launch_bounds__(256) k_init(
    const int* __restrict__ l_idx, const int* __restrict__ r_idx,
    const float* __restrict__ emb, const float* __restrict__ W_ioux,
    const float* __restrict__ b_ioux, const float* __restrict__ b_iouh,
    float* __restrict__ cmatA, float* __restrict__ matA,
    float* __restrict__ cmatB, float* __restrict__ matB)
{
  int b = blockIdx.x, tid = threadIdx.x;
  int p = b>>6, n0 = (b&63)*4;
  __shared__ __align__(16) float xs[300*4];   // xs[d*4+rr]
  for (int j = tid; j < 4*300; j += 256){
    int rr = j/300, d = j - rr*300;
    int row = p ? r_idx[n0+rr] : l_idx[n0+rr];
    xs[d*4+rr] = emb[(size_t)row*300 + d];
  }
  __syncthreads();
  int t = tid;
  const float4* wi = (const float4*)(W_ioux + (size_t)t*300);
  const float4* wo = (const float4*)(W_ioux + (size_t)(t+256)*300);
  const float4* wu = (const float4*)(W_ioux + (size_t)(t+512)*300);
  float ai[4]={0,0,0,0}, ao[4]={0,0,0,0}, au[4]={0,0,0,0};
  #pragma unroll 3
  for (int k = 0; k < 75; ++k){
    float4 a = wi[k], o = wo[k], u = wu[k];
    const float4* xp = (const float4*)(xs + k*16);
    float4 x0 = xp[0], x1 = xp[1], x2 = xp[2], x3 = xp[3];
    ai[0]+=a.x*x0.x+a.y*x1.x+a.z*x2.x+a.w*x3.x;
    ai[1]+=a.x*x0.y+a.y*x1.y+a.z*x2.y+a.w*x3.y;
    ai[2]+=a.x*x0.z+a.y*x1.z+a.z*x2.z+a.w*x3.z;
    ai[3]+=a.x*x0.w+a.y*x1.w+a.z*x2.w+a.w*x3.w;
    ao[0]+=o.x*x0.x+o.y*x1.x+o.z*x2.x+o.w*x3.x;
    ao[1]+=o.x*x0.y+o.y*x1.y+o.z*x2.y+o.w*x3.y;
    ao[2]+=o.x*x0.z+o.y*x1.z+o.z*x2.z+o.w*x3.z;
    ao[3]+=o.x*x0.w+o.y*x1.w+o.z*x2.w+o.w*x3.w;
    au[0]+=u.x*x0.x+u.y*x1.x+u.z*x2.x+u.w*x3.x;
    au[1]+=u.x*x0.y+u.y*x1.y+u.z*x2.y+u.w*x3.y;
    au[2]+=u.x*x0.z+u.y*x1.z+u.z*x2.z+u.w*x3.z;
    au[3]+=u.x*x0.w+u.y*x1.w+u.z*x2.w+u.w*x3.w;
  }
  float* cmat = p ? cmatB : cmatA;
  float* hmat = p ? matB  : matA;
  float bi = b_ioux[t]     + b_iouh[t];
  float bo = b_ioux[256+t] + b_iouh[256+t];
  float bu = b_ioux[512+t] + b_iouh[512+t];
  #pragma unroll
  for (int rr = 0; rr < 4; ++rr){
    float c = sigmf(ai[rr]+bi)*tanhfast(au[rr]+bu);
    float h = sigmf(ao[rr]+bo)*tanhfast(c);
    cmat[(size_t)(n0+rr)*256 + t] = c;
    hmat[(size_t)(n0+rr)*256 + t] = h;
  }
}

// ---------------------------------------------------------------------------
// LSTM level body, 512 threads, one output row. Group A (t<256): i,o dots;
// group B: u,f0,f1 dots -> LDS. Returns h (t<256), writes c.
// ---------------------------------------------------------------------------
__device__ __forceinline__ float lstm512(int tid, int offPrev, int offCur, int n,
    const float* __restrict__ W_iouh, const float* __restrict__ b_iouh,
    const float* __restrict__ W_fh, const float* __restrict__ b_fh,
    float* __restrict__ cmat, const float* __restrict__ hmat)
{
  __shared__ __align__(16) float hs0[256], hs1[256], hss[256];
  __shared__ float sAu[256], sF0[256], sF1[256];
  const float* h0 = hmat + (size_t)(offPrev + 2*n)*256;
  const float* h1 = h0 + 256;
  const float* c0 = cmat + (size_t)(offPrev + 2*n)*256;
  const float* c1 = c0 + 256;
  if (tid < 256) hs0[tid] = h0[tid]; else hs1[tid-256] = h1[tid-256];
  __syncthreads();
  if (tid < 256) hss[tid] = hs0[tid] + hs1[tid];
  __syncthreads();

  float ai = 0.f, ao = 0.f;
  if (tid < 256){
    const float4* wi = (const float4*)(W_iouh + (size_t)tid*256);
    const float4* wo = (const float4*)(W_iouh + (size_t)(tid+256)*256);
    const float4* sv = (const float4*)hss;
    #pragma unroll 4
    for (int k = 0; k < 64; ++k){
      float4 a = wi[k], o = wo[k], s = sv[k];
      ai += a.x*s.x + a.y*s.y + a.z*s.z + a.w*s.w;
      ao += o.x*s.x + o.y*s.y + o.z*s.z + o.w*s.w;
    }
  } else {
    int u = tid - 256;
    const float4* wu = (const float4*)(W_iouh + (size_t)(u+512)*256);
    const float4* wf = (const float4*)(W_fh + (size_t)u*256);
    const float4* sv = (const float4*)hss;
    const float4* x0 = (const float4*)hs0;
    const float4* x1 = (const float4*)hs1;
    float au = 0.f, a0 = 0.f, a1 = 0.f;
    #pragma unroll 2
    for (int k = 0; k < 64; ++k){
      float4 uu = wu[k], ff = wf[k], s = sv[k], v0 = x0[k], v1 = x1[k];
      au += uu.x*s.x + uu.y*s.y + uu.z*s.z + uu.w*s.w;
      a0 += ff.x*v0.x + ff.y*v0.y + ff.z*v0.z + ff.w*v0.w;
      a1 += ff.x*v1.x + ff.y*v1.y + ff.z*v1.z + ff.w*v1.w;
    }
    sAu[u] = au; sF0[u] = a0; sF1[u] = a1;
  }
  __syncthreads();

  float h = 0.f;
  if (tid < 256){
    int t = tid;
    float i_ = sigmf(ai + b_iouh[t]);
    float o_ = sigmf(ao + b_iouh[256+t]);
    float u_ = tanhfast(sAu[t] + b_iouh[512+t]);
    float bf = b_fh[t];
    float c = i_*u_ + sigmf(sF0[t]+bf)*c0[t] + sigmf(sF1[t]+bf)*c1[t];
    h = o_*tanhfast(c);
    cmat[(size_t)(offCur+n)*256 + t] = c;
  }
  return h;
}

// ---------------------------------------------------------------------------
// Attention for one row, 512 threads. hval valid for t<256.
// hout[t] = colsum[t] - sum_m s[m]*mat[m][t] + h[t]  (softmax sums to 1)
// No max-subtraction: |score| <= sum|Wa| ~ 10, exp safe.
// ---------------------------------------------------------------------------
__device__ void attend512(int tid, float hval,
    const float* __restrict__ W_attnh, const float* __restrict__ Wa,
    const float* __restrict__ proj,   // [m][256] (b_attnh folded in)
    const float* __restrict__ matT,   // [j][MT], m=511 zero-padded
    const float* __restrict__ colsum,
    float* __restrict__ hout)
{
  __shared__ __align__(16) float sh_h[256], sh_wa[256], php[512], sh_hp[256], sh_s[512];
  __shared__ float p0[256], p1[256], sred[8];
  int g = tid>>8, j = tid&255;
  if (tid < 256){ sh_h[tid] = hval; sh_wa[tid] = Wa[tid]; }
  __syncthreads();

  // hp partials: group g covers e in [g*128,(g+1)*128)
  {
    const float4* w = (const float4*)(W_attnh + (size_t)j*512 + g*128);
    const float4* hh = (const float4*)(sh_h + g*128);
    float a = 0.f;
    #pragma unroll 4
    for (int k = 0; k < 32; ++k){
      float4 wv = w[k], hv = hh[k];
      a += wv.x*hv.x + wv.y*hv.y + wv.z*hv.z + wv.w*hv.w;
    }
    php[g*256 + j] = a;
  }
  __syncthreads();
  if (tid < 256) sh_hp[tid] = php[tid] + php[256+tid];
  __syncthreads();

  // scores: one m per thread (m=511 -> 0)
  float e = 0.f;
  if (tid < 511){
    const float4* pr = (const float4*)(proj + (size_t)tid*256);
    const float4* hp4 = (const float4*)sh_hp;
    const float4* wa4 = (const float4*)sh_wa;
    float s = 0.f;
    #pragma unroll 2
    for (int k = 0; k < 64; ++k){
      float4 pv = pr[k], hv = hp4[k], wv = wa4[k];
      s += wv.x*tanhfast(hv.x+pv.x);
      s += wv.y*tanhfast(hv.y+pv.y);
      s += wv.z*tanhfast(hv.z+pv.z);
      s += wv.w*tanhfast(hv.w+pv.w);
    }
    e = __expf(s);
  }
  // block sum of e
  float r = e;
  #pragma unroll
  for (int off = 32; off; off >>= 1) r += __shfl_down(r, off);
  if ((tid&63) == 0) sred[tid>>6] = r;
  __syncthreads();
  float tot = sred[0]+sred[1]+sred[2]+sred[3]+sred[4]+sred[5]+sred[6]+sred[7];
  sh_s[tid] = e / tot;
  __syncthreads();

  // weighted sum via matT (contiguous float4 per thread), m-split by group
  {
    const float4* mt = (const float4*)(matT + (size_t)j*MT + g*256);
    const float4* ss = (const float4*)(sh_s + g*256);
    float a = 0.f;
    #pragma unroll 4
    for (int k = 0; k < 64; ++k){
      float4 mv = mt[k], sv = ss[k];
      a += mv.x*sv.x + mv.y*sv.y + mv.z*sv.z + mv.w*sv.w;
    }
    if (g == 0) p0[j] = a; else p1[j] = a;
  }
  __syncthreads();
  if (tid < 256) hout[tid] = colsum[tid] - (p0[tid] + p1[tid]) + sh_h[tid];
}

// ---------------------------------------------------------------------------
// A/B tree level: block per output row (both passes), 512 threads.
// ---------------------------------------------------------------------------
__global__ void __launch_bounds__(512) k_levelAB(
    const float* __restrict__ W_iouh, const float* __restrict__ b_iouh,
    const float* __restrict__ W_fh, const float* __restrict__ b_fh,
    int Nc, int offPrev, int offCur,
    float* __restrict__ cmatA, float* __restrict__ matA,
    float* __restrict__ cmatB, float* __restrict__ matB)
{
  int b = blockIdx.x, tid = threadIdx.x;
  bool isA = (b < Nc); int n = isA ? b : b - Nc;
  float* cmat = isA ? cmatA : cmatB;
  float* hmat = isA ? matA  : matB;
  float h = lstm512(tid, offPrev, offCur, n, W_iouh, b_iouh, W_fh, b_fh, cmat, hmat);
  if (tid < 256) hmat[(size_t)(offCur+n)*256 + tid] = h;
}

// ---------------------------------------------------------------------------
// Mid kernel: proj rows (blocks 0..127, 8 m/block), colsums (128,129),
// mat transposes with zero pad (130..385).
// ---------------------------------------------------------------------------
__global__ void __launch_bounds__(256) k_mid(
    const float* __restrict__ W_attnh, const float* __restrict__ b_attnh,
    const float* __restrict__ matA, const float* __restrict__ matB,
    float* __restrict__ projA, float* __restrict__ projB,
    float* __restrict__ colA, float* __restrict__ colB,
    float* __restrict__ matTA, float* __restrict__ matTB)
{
  int b = blockIdx.x, tid = threadIdx.x;
  if (b < 128){
    int p = b>>6, ch = b&63, m0 = ch*8, mc = min(8, 511-m0);
    const float* mat = p ? matB : matA;
    float* proj = p ? projB : projA;
    __shared__ __align__(16) float ms[256*8];   // ms[e*8+rr]
    for (int j = tid; j < mc*256; j += 256){
      int rr = j>>8, e = j&255;
      ms[e*8+rr] = mat[(size_t)(m0+rr)*256 + e];
    }
    for (int j = tid + mc*256; j < 8*256; j += 256){
      int rr = j>>8, e = j&255; ms[e*8+rr] = 0.f;
    }
    __syncthreads();
    int t = tid;
    const float4* w2 = (const float4*)(W_attnh + (size_t)t*512 + 256);
    float acc[8] = {0,0,0,0,0,0,0,0};
    #pragma unroll 2
    for (int k = 0; k < 64; ++k){
      float4 w = w2[k];
      const float* base = ms + k*32;
      #pragma unroll
      for (int rr = 0; rr < 8; ++rr)
        acc[rr] += w.x*base[rr] + w.y*base[8+rr] + w.z*base[16+rr] + w.w*base[24+rr];
    }
    float ba = b_attnh[t];
    for (int rr = 0; rr < mc; ++rr) proj[(size_t)(m0+rr)*256 + t] = acc[rr] + ba;
  } else if (b < 130){
    int p = b - 128;
    const float* mat = p ? matB : matA;
    float* col = p ? colB : colA;
    float s = 0.f;
    #pragma unroll 8
    for (int m = 0; m < 511; ++m) s += mat[(size_t)m*256 + tid];
    col[tid] = s;
  } else {
    int idx = b - 130;
    int p = idx>>7, rem = idx&127, jt = rem>>4, mt = rem&15;
    const float* mat = p ? matB : matA;
    float* matT = p ? matTB : matTA;
    __shared__ float tile[32][33];
    int c = tid&31, r0 = tid>>5;
    int m0 = mt*32, j0 = jt*32;
    #pragma unroll
    for (int k = 0; k < 4; ++k){
      int m = m0 + r0 + 8*k;
      tile[r0+8*k][c] = (m < 511) ? mat[(size_t)m*256 + j0 + c] : 0.f;
    }
    __syncthreads();
    #pragma unroll
    for (int k = 0; k < 4; ++k){
      int jj = r0 + 8*k;
      matT[(size_t)(j0+jj)*MT + m0 + c] = tile[c][jj];
    }
  }
}

// ---------------------------------------------------------------------------
// Attend-init for C/D (row 0..255 of each): copy c, attend initial h.
// ---------------------------------------------------------------------------
__global__ void __launch_bounds__(512) k_attinit(
    const float* __restrict__ W_attnh, const float* __restrict__ Wa,
    const float* __restrict__ matA, const float* __restrict__ matB,
    const float* __restrict__ projA, const float* __restrict__ projB,
    const float* __restrict__ matTA, const float* __restrict__ matTB,
    const float* __restrict__ colA, const float* __restrict__ colB,
    const float* __restrict__ cmatA, const float* __restrict__ cmatB,
    float* __restrict__ cmatC, float* __restrict__ hC,
    float* __restrict__ cmatD, float* __restrict__ hD)
{
  int b = blockIdx.x, tid = threadIdx.x;
  bool isC = (b < 256); int r = isC ? b : b - 256;
  const float* hsrc = (isC ? matB  : matA)  + (size_t)r*256;
  const float* csrc = (isC ? cmatB : cmatA) + (size_t)r*256;
  float* cdst = (isC ? cmatC : cmatD) + (size_t)r*256;
  float hval = 0.f;
  if (tid < 256){ cdst[tid] = csrc[tid]; hval = hsrc[tid]; }
  attend512(tid, hval, W_attnh, Wa,
            isC ? projA : projB, isC ? matTA : matTB, isC ? colA : colB,
            (isC ? hC : hD) + (size_t)r*256);
}

// ---------------------------------------------------------------------------
// C/D tree level: fused LSTM + attend, block per output row, 512 threads.
// ---------------------------------------------------------------------------
__global__ void __launch_bounds__(512) k_levelCD(
    const float* __restrict__ W_iouh, const float* __restrict__ b_iouh,
    const float* __restrict__ W_fh, const float* __restrict__ b_fh,
    const float* __restrict__ W_attnh, const float* __restrict__ Wa,
    int Nc, int offPrev, int offCur,
    float* __restrict__ cmatC, float* __restrict__ hC,
    const float* __restrict__ projA, const float* __restrict__ matTA,
    const float* __restrict__ colA,
    float* __restrict__ cmatD, float* __restrict__ hD,
    const float* __restrict__ projB, const float* __restrict__ matTB,
    const float* __restrict__ colB)
{
  int b = blockIdx.x, tid = threadIdx.x;
  bool isC = (b < Nc); int n = isC ? b : b - Nc;
  float* cmat = isC ? cmatC : cmatD;
  float* hmat = isC ? hC : hD;
  float h = lstm512(tid, offPrev, offCur, n, W_iouh, b_iouh, W_fh, b_fh, cmat, hmat);
  attend512(tid, h, W_attnh, Wa,
            isC ? projA : projB, isC ? matTA : matTB, isC ? colA : colB,
            hmat + (size_t)(offCur+n)*256);
}

// ---------------------------------------------------------------------------
// Head MLP + log_softmax, 1 block x 256.
// ---------------------------------------------------------------------------
__global__ void __launch_bounds__(256) k_head(
    const float* __restrict__ W_wh, const float* __restrict__ b_wh,
    const float* __restrict__ W_wp, const float* __restrict__ b_wp,
    const float* __restrict__ lh1, const float* __restrict__ rh1,
    const float* __restrict__ rh2, const float* __restrict__ lh2,
    float* __restrict__ out)
{
  __shared__ __align__(16) float v[512];
  __shared__ float og[128], lg[5];
  int t = threadIdx.x;
  {
    float lh = tanhfast(lh1[t] + lh2[t]);
    float rh = tanhfast(rh1[t] + rh2[t]);
    v[t] = lh*rh;
    v[256+t] = fabsf(lh - rh);
  }
  __syncthreads();
  if (t < 128){
    const float4* w = (const float4*)(W_wh + (size_t)t*512);
    const float4* vv = (const float4*)v;
    float a = b_wh[t];
    #pragma unroll 4
    for (int k = 0; k < 128; ++k){
      float4 wv = w[k], x = vv[k];
      a += wv.x*x.x + wv.y*x.y + wv.z*x.z + wv.w*x.w;
    }
    og[t] = sigmf(a);
  }
  __syncthreads();
  if (t < 5){
    const float* wp = W_wp + (size_t)t*128;
    float a = b_wp[t];
    for (int j = 0; j < 128; ++j) a += og[j]*wp[j];
    lg[t] = a;
  }
  __syncthreads();
  if (t == 0){
    float M = -1e30f;
    for (int c = 0; c < 5; ++c) M = fmaxf(M, lg[c]);
    float S = 0.f;
    for (int c = 0; c < 5; ++c) S += __expf(lg[c] - M);
    float L = logf(S);
    for (int c = 0; c < 5; ++c) out[c] = lg[c] - M - L;
  }
}

extern "C" void kernel_launch(void* const* d_in, const int* in_sizes, int n_in,
                              void* d_out, int out_size, void* d_ws, size_t ws_size,
                              hipStream_t stream)
{
  const int*   l_idx   = (const int*)  d_in[0];
  const int*   r_idx   = (const int*)  d_in[1];
  const float* emb     = (const float*)d_in[2];
  const float* W_ioux  = (const float*)d_in[3];
  const float* b_ioux  = (const float*)d_in[4];
  const float* W_iouh  = (const float*)d_in[5];
  const float* b_iouh  = (const float*)d_in[6];
  // d_in[7]=W_fx, d_in[8]=b_fx unused by the forward
  const float* W_fh    = (const float*)d_in[9];
  const float* b_fh    = (const float*)d_in[10];
  const float* Wa      = (const float*)d_in[11];
  const float* W_attnh = (const float*)d_in[12];
  const float* b_attnh = (const float*)d_in[13];
  const float* W_wh    = (const float*)d_in[14];
  const float* b_wh    = (const float*)d_in[15];
  const float* W_wp    = (const float*)d_in[16];
  const float* b_wp    = (const float*)d_in[17];

  float* ws = (float*)d_ws;
  float* cmatA = ws;            float* cmatB = cmatA + RC;
  float* cmatC = cmatB + RC;    float* cmatD = cmatC + RC;
  float* matA  = cmatD + RC;    float* matB  = matA + RC;
  float* hC    = matB + RC;     float* hD    = hC + RC;
  float* projA = hD + RC;       float* projB = projA + RC;
  float* matTA = projB + RC;    float* matTB = matTA + 256*MT;
  float* colA  = matTB + 256*MT;
  float* colB  = colA + 256;
  // total ~6.3 MB

  static const int offs[9] = {0, 256, 384, 448, 480, 496, 504, 508, 510};

  k_init<<<128, 256, 0, stream>>>(l_idx, r_idx, emb, W_ioux, b_ioux, b_iouh,
                                  cmatA, matA, cmatB, matB);
  for (int i = 1; i <= 8; ++i){
    int Nc = 256 >> i;
    k_levelAB<<<2*Nc, 512, 0, stream>>>(W_iouh, b_iouh, W_fh, b_fh,
                                        Nc, offs[i-1], offs[i],
                                        cmatA, matA, cmatB, matB);
  }
  k_mid<<<386, 256, 0, stream>>>(W_attnh, b_attnh, matA, matB,
                                 projA, projB, colA, colB, matTA, matTB);
  k_attinit<<<512, 512, 0, stream>>>(W_attnh, Wa, matA, matB, projA, projB,
                                     matTA, matTB, colA, colB, cmatA, cmatB,
                                     cmatC, hC, cmatD, hD);
  for (int i = 1; i <= 8; ++i){
    int Nc = 256 >> i;
    k_levelCD<<<2*Nc, 512, 0, stream>>>(W_iouh, b_iouh, W_fh, b_fh, W_attnh, Wa,
                                        Nc, offs[i-1], offs[i],
                                        cmatC, hC, projA, matTA, colA,
                                        cmatD, hD, projB, matTB, colB);
  }
  k_head<<<1, 256, 0, stream>>>(W_wh, b_wh, W_wp, b_wp,
                                matA + (size_t)510*256,   // lh1
                                hC   + (size_t)510*256,   // rh1
                                matB + (size_t)510*256,   // rh2
                                hD   + (size_t)510*256,   // lh2
                                (float*)d_out);
}

// Round 6
// 922.847 us; speedup vs baseline: 2.7649x; 1.2385x over previous
//
#include <hip/hip_runtime.h>

#define RC 130816   // 511*256
#define MT 512      // matT m-stride (511 zero-padded)

__device__ __forceinline__ float rcpf(float x){ return __builtin_amdgcn_rcpf(x); }
__device__ __forceinline__ float sigmf(float x){ return rcpf(1.f + __expf(-x)); }
__device__ __forceinline__ float tanhfast(float x){
  // 1 - 2/(e^{2x}+1); saturates to +/-1 at inf, no NaN, no clamp needed
  return 1.f - 2.f*rcpf(1.f + __expf(2.f*x));
}

// ---------------------------------------------------------------------------
// Init: block = (pass p, 4 rows); per-thread contiguous float4 W_ioux streams.
// ---------------------------------------------------------------------------
__global__ void __launch_bounds__(256) k_init(
    const int* __restrict__ l_idx, const int* __restrict__ r_idx,
    const float* __restrict__ emb, const float* __restrict__ W_ioux,
    const float* __restrict__ b_ioux, const float* __restrict__ b_iouh,
    float* __restrict__ cmatA, float* __restrict__ matA,
    float* __restrict__ cmatB, float* __restrict__ matB)
{
  int b = blockIdx.x, tid = threadIdx.x;
  int p = b>>6, n0 = (b&63)*4;
  __shared__ __align__(16) float xs[300*4];   // xs[d*4+rr]
  for (int j = tid; j < 4*300; j += 256){
    int rr = j/300, d = j - rr*300;
    int row = p ? r_idx[n0+rr] : l_idx[n0+rr];
    xs[d*4+rr] = emb[(size_t)row*300 + d];
  }
  __syncthreads();
  int t = tid;
  const float4* wi = (const float4*)(W_ioux + (size_t)t*300);
  const float4* wo = (const float4*)(W_ioux + (size_t)(t+256)*300);
  const float4* wu = (const float4*)(W_ioux + (size_t)(t+512)*300);
  float ai[4]={0,0,0,0}, ao[4]={0,0,0,0}, au[4]={0,0,0,0};
  #pragma unroll 3
  for (int k = 0; k < 75; ++k){
    float4 a = wi[k], o = wo[k], u = wu[k];
    const float4* xp = (const float4*)(xs + k*16);
    float4 x0 = xp[0], x1 = xp[1], x2 = xp[2], x3 = xp[3];
    ai[0]+=a.x*x0.x+a.y*x1.x+a.z*x2.x+a.w*x3.x;
    ai[1]+=a.x*x0.y+a.y*x1.y+a.z*x2.y+a.w*x3.y;
    ai[2]+=a.x*x0.z+a.y*x1.z+a.z*x2.z+a.w*x3.z;
    ai[3]+=a.x*x0.w+a.y*x1.w+a.z*x2.w+a.w*x3.w;
    ao[0]+=o.x*x0.x+o.y*x1.x+o.z*x2.x+o.w*x3.x;
    ao[1]+=o.x*x0.y+o.y*x1.y+o.z*x2.y+o.w*x3.y;
    ao[2]+=o.x*x0.z+o.y*x1.z+o.z*x2.z+o.w*x3.z;
    ao[3]+=o.x*x0.w+o.y*x1.w+o.z*x2.w+o.w*x3.w;
    au[0]+=u.x*x0.x+u.y*x1.x+u.z*x2.x+u.w*x3.x;
    au[1]+=u.x*x0.y+u.y*x1.y+u.z*x2.y+u.w*x3.y;
    au[2]+=u.x*x0.z+u.y*x1.z+u.z*x2.z+u.w*x3.z;
    au[3]+=u.x*x0.w+u.y*x1.w+u.z*x2.w+u.w*x3.w;
  }
  float* cmat = p ? cmatB : cmatA;
  float* hmat = p ? matB  : matA;
  float bi = b_ioux[t]     + b_iouh[t];
  float bo = b_ioux[256+t] + b_iouh[256+t];
  float bu = b_ioux[512+t] + b_iouh[512+t];
  #pragma unroll
  for (int rr = 0; rr < 4; ++rr){
    float c = sigmf(ai[rr]+bi)*tanhfast(au[rr]+bu);
    float h = sigmf(ao[rr]+bo)*tanhfast(c);
    cmat[(size_t)(n0+rr)*256 + t] = c;
    hmat[(size_t)(n0+rr)*256 + t] = h;
  }
}

// ---------------------------------------------------------------------------
// A/B tree level (no attention): block per output row, 512 threads.
// ---------------------------------------------------------------------------
__global__ void __launch_bounds__(512) k_levelAB(
    const float* __restrict__ W_iouh, const float* __restrict__ b_iouh,
    const float* __restrict__ W_fh, const float* __restrict__ b_fh,
    int Nc, int offPrev, int offCur,
    float* __restrict__ cmatA, float* __restrict__ matA,
    float* __restrict__ cmatB, float* __restrict__ matB)
{
  int b = blockIdx.x, tid = threadIdx.x;
  bool isA = (b < Nc); int n = isA ? b : b - Nc;
  float* cmat = isA ? cmatA : cmatB;
  float* hmat = isA ? matA  : matB;

  __shared__ __align__(16) float hs0[256], hs1[256], hss[256];
  __shared__ float sAu[256], sF0[256], sF1[256];
  const float* h0 = hmat + (size_t)(offPrev + 2*n)*256;
  const float* h1 = h0 + 256;
  const float* c0 = cmat + (size_t)(offPrev + 2*n)*256;
  const float* c1 = c0 + 256;
  if (tid < 256) hs0[tid] = h0[tid]; else hs1[tid-256] = h1[tid-256];
  __syncthreads();
  if (tid < 256) hss[tid] = hs0[tid] + hs1[tid];
  __syncthreads();

  float ai = 0.f, ao = 0.f;
  if (tid < 256){
    const float4* wi = (const float4*)(W_iouh + (size_t)tid*256);
    const float4* wo = (const float4*)(W_iouh + (size_t)(tid+256)*256);
    const float4* sv = (const float4*)hss;
    #pragma unroll 4
    for (int k = 0; k < 64; ++k){
      float4 a = wi[k], o = wo[k], s = sv[k];
      ai += a.x*s.x + a.y*s.y + a.z*s.z + a.w*s.w;
      ao += o.x*s.x + o.y*s.y + o.z*s.z + o.w*s.w;
    }
  } else {
    int u = tid - 256;
    const float4* wu = (const float4*)(W_iouh + (size_t)(u+512)*256);
    const float4* wf = (const float4*)(W_fh + (size_t)u*256);
    const float4* sv = (const float4*)hss;
    const float4* x0 = (const float4*)hs0;
    const float4* x1 = (const float4*)hs1;
    float au = 0.f, a0 = 0.f, a1 = 0.f;
    #pragma unroll 2
    for (int k = 0; k < 64; ++k){
      float4 uu = wu[k], ff = wf[k], s = sv[k], v0 = x0[k], v1 = x1[k];
      au += uu.x*s.x + uu.y*s.y + uu.z*s.z + uu.w*s.w;
      a0 += ff.x*v0.x + ff.y*v0.y + ff.z*v0.z + ff.w*v0.w;
      a1 += ff.x*v1.x + ff.y*v1.y + ff.z*v1.z + ff.w*v1.w;
    }
    sAu[u] = au; sF0[u] = a0; sF1[u] = a1;
  }
  __syncthreads();
  if (tid < 256){
    int t = tid;
    float i_ = sigmf(ai + b_iouh[t]);
    float o_ = sigmf(ao + b_iouh[256+t]);
    float u_ = tanhfast(sAu[t] + b_iouh[512+t]);
    float bf = b_fh[t];
    float c = i_*u_ + sigmf(sF0[t]+bf)*c0[t] + sigmf(sF1[t]+bf)*c1[t];
    float h = o_*tanhfast(c);
    cmat[(size_t)(offCur+n)*256 + t] = c;
    hmat[(size_t)(offCur+n)*256 + t] = h;
  }
}

// ---------------------------------------------------------------------------
// Mid: proj rows (0..127), colsums (128,129), matT transposes (130..385),
// hp for the 512 init rows of C/D (386..449).
// hpC <- matB @ W1^T ; hpD <- matA @ W1^T.  (C's h0 = pass-B rows.)
// ---------------------------------------------------------------------------
__global__ void __launch_bounds__(256) k_mid(
    const float* __restrict__ W_attnh, const float* __restrict__ b_attnh,
    const float* __restrict__ matA, const float* __restrict__ matB,
    float* __restrict__ projA, float* __restrict__ projB,
    float* __restrict__ colA, float* __restrict__ colB,
    float* __restrict__ matTA, float* __restrict__ matTB,
    float* __restrict__ hpC, float* __restrict__ hpD)
{
  int b = blockIdx.x, tid = threadIdx.x;
  if (b < 128){
    int p = b>>6, ch = b&63, m0 = ch*8, mc = min(8, 511-m0);
    const float* mat = p ? matB : matA;
    float* proj = p ? projB : projA;
    __shared__ __align__(16) float ms[256*8];   // ms[e*8+rr]
    for (int j = tid; j < mc*256; j += 256){
      int rr = j>>8, e = j&255;
      ms[e*8+rr] = mat[(size_t)(m0+rr)*256 + e];
    }
    for (int j = tid + mc*256; j < 8*256; j += 256){
      int rr = j>>8, e = j&255; ms[e*8+rr] = 0.f;
    }
    __syncthreads();
    int t = tid;
    const float4* w2 = (const float4*)(W_attnh + (size_t)t*512 + 256);
    float acc[8] = {0,0,0,0,0,0,0,0};
    #pragma unroll 2
    for (int k = 0; k < 64; ++k){
      float4 w = w2[k];
      const float* base = ms + k*32;
      #pragma unroll
      for (int rr = 0; rr < 8; ++rr)
        acc[rr] += w.x*base[rr] + w.y*base[8+rr] + w.z*base[16+rr] + w.w*base[24+rr];
    }
    float ba = b_attnh[t];
    for (int rr = 0; rr < mc; ++rr) proj[(size_t)(m0+rr)*256 + t] = acc[rr] + ba;
  } else if (b < 130){
    int p = b - 128;
    const float* mat = p ? matB : matA;
    float* col = p ? colB : colA;
    float s = 0.f;
    #pragma unroll 8
    for (int m = 0; m < 511; ++m) s += mat[(size_t)m*256 + tid];
    col[tid] = s;
  } else if (b < 386){
    int idx = b - 130;
    int p = idx>>7, rem = idx&127, jt = rem>>4, mt = rem&15;
    const float* mat = p ? matB : matA;
    float* matT = p ? matTB : matTA;
    __shared__ float tile[32][33];
    int c = tid&31, r0 = tid>>5;
    int m0 = mt*32, j0 = jt*32;
    #pragma unroll
    for (int k = 0; k < 4; ++k){
      int m = m0 + r0 + 8*k;
      tile[r0+8*k][c] = (m < 511) ? mat[(size_t)m*256 + j0 + c] : 0.f;
    }
    __syncthreads();
    #pragma unroll
    for (int k = 0; k < 4; ++k){
      int jj = r0 + 8*k;
      matT[(size_t)(j0+jj)*MT + m0 + c] = tile[c][jj];
    }
  } else {
    int idx = b - 386;           // 64 blocks: p (C/D) x 32 chunks of 8 rows
    int p = idx>>5, ch = idx&31, r0 = ch*8;
    const float* hsrc = p ? matA : matB;   // C<-B, D<-A
    float* hp = p ? hpD : hpC;
    __shared__ __align__(16) float ms[256*8];
    for (int j = tid; j < 8*256; j += 256){
      int rr = j>>8, e = j&255;
      ms[e*8+rr] = hsrc[(size_t)(r0+rr)*256 + e];
    }
    __syncthreads();
    int t = tid;
    const float4* w1 = (const float4*)(W_attnh + (size_t)t*512);
    float acc[8] = {0,0,0,0,0,0,0,0};
    #pragma unroll 2
    for (int k = 0; k < 64; ++k){
      float4 w = w1[k];
      const float* base = ms + k*32;
      #pragma unroll
      for (int rr = 0; rr < 8; ++rr)
        acc[rr] += w.x*base[rr] + w.y*base[8+rr] + w.z*base[16+rr] + w.w*base[24+rr];
    }
    #pragma unroll
    for (int rr = 0; rr < 8; ++rr) hp[(size_t)(r0+rr)*256 + t] = acc[rr];
  }
}

// ---------------------------------------------------------------------------
// Scores: block = (pass, row n, m-chunk of 128). 256 threads = 128 m x 2 d-halves.
// Writes unnormalized wsumP[p][row][ch][256] and esumP[p][row][ch].
// ---------------------------------------------------------------------------
__global__ void __launch_bounds__(256) k_scores(
    const float* __restrict__ hpC, const float* __restrict__ hpD,
    const float* __restrict__ projA, const float* __restrict__ projB,
    const float* __restrict__ matTA, const float* __restrict__ matTB,
    const float* __restrict__ Wa,
    int Nc, int rowOff,
    float* __restrict__ wsumP, float* __restrict__ esumP)
{
  int b = blockIdx.x, tid = threadIdx.x;
  int per = Nc*4;
  int p = b / per; int rem = b - p*per; int n = rem>>2, ch = rem&3;
  int row = rowOff + n;
  const float* hp = (p ? hpD : hpC) + (size_t)row*256;
  const float* proj = p ? projB : projA;
  const float* matT = p ? matTB : matTA;
  __shared__ __align__(16) float shp[256], swa[256], sp[256], se[128];
  shp[tid] = hp[tid]; swa[tid] = Wa[tid];
  __syncthreads();
  int mloc = tid & 127, half = tid >> 7;
  int m0 = ch*128, m = m0 + mloc;
  float partial = 0.f;
  if (m < 511){
    const float4* pr = (const float4*)(proj + (size_t)m*256 + half*128);
    const float4* hp4 = (const float4*)(shp + half*128);
    const float4* wa4 = (const float4*)(swa + half*128);
    #pragma unroll 4
    for (int k = 0; k < 32; ++k){
      float4 pv = pr[k], hv = hp4[k], wv = wa4[k];
      partial += wv.x*tanhfast(hv.x+pv.x) + wv.y*tanhfast(hv.y+pv.y)
               + wv.z*tanhfast(hv.z+pv.z) + wv.w*tanhfast(hv.w+pv.w);
    }
  }
  sp[tid] = partial;
  __syncthreads();
  if (tid < 128){
    float e = (m0 + tid < 511) ? __expf(sp[tid] + sp[tid+128]) : 0.f;
    se[tid] = e;
  }
  __syncthreads();
  // unnormalized weighted sum over this chunk (matT pad row m=511 is 0)
  {
    const float4* mt = (const float4*)(matT + (size_t)tid*MT + m0);
    const float4* es4 = (const float4*)se;
    float y = 0.f;
    #pragma unroll 4
    for (int k = 0; k < 32; ++k){
      float4 mv = mt[k], ev = es4[k];
      y += mv.x*ev.x + mv.y*ev.y + mv.z*ev.z + mv.w*ev.w;
    }
    wsumP[(((size_t)p*511 + row)*4 + ch)*256 + tid] = y;
  }
  if (tid < 64){
    float s2 = se[tid] + se[tid+64];
    #pragma unroll
    for (int off = 32; off; off >>= 1) s2 += __shfl_down(s2, off);
    if (tid == 0) esumP[((size_t)p*511 + row)*4 + ch] = s2;
  }
}

// ---------------------------------------------------------------------------
// CD spine: finish children's attend from partials, LSTM, h_pre + hp out.
// Block per output row (C then D), 512 threads.
// ---------------------------------------------------------------------------
__global__ void __launch_bounds__(512) k_cd1(
    const float* __restrict__ W_iouh, const float* __restrict__ b_iouh,
    const float* __restrict__ W_fh, const float* __restrict__ b_fh,
    const float* __restrict__ W_attnh,
    int Nc, int offPrev, int offCur,
    const float* __restrict__ colA, const float* __restrict__ colB,
    const float* __restrict__ wsumP, const float* __restrict__ esumP,
    const float* __restrict__ childHC, const float* __restrict__ childHD,
    const float* __restrict__ childCC, const float* __restrict__ childCD_,
    float* __restrict__ cmatC, float* __restrict__ cmatD,
    float* __restrict__ hstageC, float* __restrict__ hstageD,
    float* __restrict__ hpC, float* __restrict__ hpD)
{
  int b = blockIdx.x, tid = threadIdx.x;
  bool isC = (b < Nc); int n = isC ? b : b - Nc;
  int p = isC ? 0 : 1;
  const float* col    = isC ? colA : colB;
  const float* childH = isC ? childHC : childHD;
  const float* childC = isC ? childCC : childCD_;
  float* cmat   = isC ? cmatC : cmatD;
  float* hstage = isC ? hstageC : hstageD;
  float* hpbuf  = isC ? hpC : hpD;

  __shared__ __align__(16) float hs0[256], hs1[256], hss[256];
  __shared__ float sAu[256], sF0[256], sF1[256];
  __shared__ __align__(16) float shh[256], php[512];

  // finish attend of the two children rows
  {
    int ch = tid >> 8, j = tid & 255;
    int r = offPrev + 2*n + ch;
    const float* wp = wsumP + (((size_t)p*511 + r)*4)*256;
    float w = wp[j] + wp[256+j] + wp[512+j] + wp[768+j];
    const float* ep = esumP + ((size_t)p*511 + r)*4;
    float esum = ep[0]+ep[1]+ep[2]+ep[3];
    float hatt = col[j] - w*rcpf(esum) + childH[(size_t)r*256 + j];
    if (ch) hs1[j] = hatt; else hs0[j] = hatt;
  }
  __syncthreads();
  if (tid < 256) hss[tid] = hs0[tid] + hs1[tid];
  __syncthreads();

  const float* c0 = childC + (size_t)(offPrev + 2*n)*256;
  const float* c1 = c0 + 256;
  float ai = 0.f, ao = 0.f;
  if (tid < 256){
    const float4* wi = (const float4*)(W_iouh + (size_t)tid*256);
    const float4* wo = (const float4*)(W_iouh + (size_t)(tid+256)*256);
    const float4* sv = (const float4*)hss;
    #pragma unroll 4
    for (int k = 0; k < 64; ++k){
      float4 a = wi[k], o = wo[k], s = sv[k];
      ai += a.x*s.x + a.y*s.y + a.z*s.z + a.w*s.w;
      ao += o.x*s.x + o.y*s.y + o.z*s.z + o.w*s.w;
    }
  } else {
    int u = tid - 256;
    const float4* wu = (const float4*)(W_iouh + (size_t)(u+512)*256);
    const float4* wf = (const float4*)(W_fh + (size_t)u*256);
    const float4* sv = (const float4*)hss;
    const float4* x0 = (const float4*)hs0;
    const float4* x1 = (const float4*)hs1;
    float au = 0.f, a0 = 0.f, a1 = 0.f;
    #pragma unroll 2
    for (int k = 0; k < 64; ++k){
      float4 uu = wu[k], ff = wf[k], s = sv[k], v0 = x0[k], v1 = x1[k];
      au += uu.x*s.x + uu.y*s.y + uu.z*s.z + uu.w*s.w;
      a0 += ff.x*v0.x + ff.y*v0.y + ff.z*v0.z + ff.w*v0.w;
      a1 += ff.x*v1.x + ff.y*v1.y + ff.z*v1.z + ff.w*v1.w;
    }
    sAu[u] = au; sF0[u] = a0; sF1[u] = a1;
  }
  __syncthreads();
  if (tid < 256){
    int t = tid;
    float i_ = sigmf(ai + b_iouh[t]);
    float o_ = sigmf(ao + b_iouh[256+t]);
    float u_ = tanhfast(sAu[t] + b_iouh[512+t]);
    float bf = b_fh[t];
    float c = i_*u_ + sigmf(sF0[t]+bf)*c0[t] + sigmf(sF1[t]+bf)*c1[t];
    float h = o_*tanhfast(c);
    cmat[(size_t)(offCur+n)*256 + t] = c;
    hstage[(size_t)(offCur+n)*256 + t] = h;
    shh[t] = h;
  }
  __syncthreads();
  // hp = h_pre @ W1^T (split e-range across the two thread groups)
  {
    int g = tid>>8, j = tid&255;
    const float4* w = (const float4*)(W_attnh + (size_t)j*512 + g*128);
    const float4* hh = (const float4*)(shh + g*128);
    float a = 0.f;
    #pragma unroll 4
    for (int k = 0; k < 32; ++k){
      float4 wv = w[k], hv = hh[k];
      a += wv.x*hv.x + wv.y*hv.y + wv.z*hv.z + wv.w*hv.w;
    }
    php[g*256 + j] = a;
  }
  __syncthreads();
  if (tid < 256) hpbuf[(size_t)(offCur+n)*256 + tid] = php[tid] + php[256+tid];
}

// ---------------------------------------------------------------------------
// Head: finish row 510 of C and D, then MLP + log_softmax. 1 block x 256.
// ---------------------------------------------------------------------------
__global__ void __launch_bounds__(256) k_head(
    const float* __restrict__ W_wh, const float* __restrict__ b_wh,
    const float* __restrict__ W_wp, const float* __restrict__ b_wp,
    const float* __restrict__ matA, const float* __restrict__ matB,
    const float* __restrict__ colA, const float* __restrict__ colB,
    const float* __restrict__ wsumP, const float* __restrict__ esumP,
    const float* __restrict__ hstageC, const float* __restrict__ hstageD,
    float* __restrict__ out)
{
  __shared__ __align__(16) float v[512];
  __shared__ float og[128], lg[5];
  int t = threadIdx.x;
  {
    // finish C (p=0) and D (p=1) row 510
    const float* wpC = wsumP + (((size_t)0*511 + 510)*4)*256;
    const float* epC = esumP + ((size_t)0*511 + 510)*4;
    float wC = wpC[t] + wpC[256+t] + wpC[512+t] + wpC[768+t];
    float eC = epC[0]+epC[1]+epC[2]+epC[3];
    float hCf = colA[t] - wC*rcpf(eC) + hstageC[(size_t)510*256 + t];
    const float* wpD = wsumP + (((size_t)1*511 + 510)*4)*256;
    const float* epD = esumP + ((size_t)1*511 + 510)*4;
    float wD = wpD[t] + wpD[256+t] + wpD[512+t] + wpD[768+t];
    float eD = epD[0]+epD[1]+epD[2]+epD[3];
    float hDf = colB[t] - wD*rcpf(eD) + hstageD[(size_t)510*256 + t];
    float lh = tanhfast(matA[(size_t)510*256 + t] + hDf);  // lh1 + lh2
    float rh = tanhfast(hCf + matB[(size_t)510*256 + t]);  // rh1 + rh2
    v[t] = lh*rh;
    v[256+t] = fabsf(lh - rh);
  }
  __syncthreads();
  if (t < 128){
    const float4* w = (const float4*)(W_wh + (size_t)t*512);
    const float4* vv = (const float4*)v;
    float a = b_wh[t];
    #pragma unroll 4
    for (int k = 0; k < 128; ++k){
      float4 wv = w[k], x = vv[k];
      a += wv.x*x.x + wv.y*x.y + wv.z*x.z + wv.w*x.w;
    }
    og[t] = sigmf(a);
  }
  __syncthreads();
  if (t < 5){
    const float* wp = W_wp + (size_t)t*128;
    float a = b_wp[t];
    for (int j = 0; j < 128; ++j) a += og[j]*wp[j];
    lg[t] = a;
  }
  __syncthreads();
  if (t == 0){
    float M = -1e30f;
    for (int c = 0; c < 5; ++c) M = fmaxf(M, lg[c]);
    float S = 0.f;
    for (int c = 0; c < 5; ++c) S += __expf(lg[c] - M);
    float L = logf(S);
    for (int c = 0; c < 5; ++c) out[c] = lg[c] - M - L;
  }
}

extern "C" void kernel_launch(void* const* d_in, const int* in_sizes, int n_in,
                              void* d_out, int out_size, void* d_ws, size_t ws_size,
                              hipStream_t stream)
{
  const int*   l_idx   = (const int*)  d_in[0];
  const int*   r_idx   = (const int*)  d_in[1];
  const float* emb     = (const float*)d_in[2];
  const float* W_ioux  = (const float*)d_in[3];
  const float* b_ioux  = (const float*)d_in[4];
  const float* W_iouh  = (const float*)d_in[5];
  const float* b_iouh  = (const float*)d_in[6];
  // d_in[7]=W_fx, d_in[8]=b_fx unused by the forward
  const float* W_fh    = (const float*)d_in[9];
  const float* b_fh    = (const float*)d_in[10];
  const float* Wa      = (const float*)d_in[11];
  const float* W_attnh = (const float*)d_in[12];
  const float* b_attnh = (const float*)d_in[13];
  const float* W_wh    = (const float*)d_in[14];
  const float* b_wh    = (const float*)d_in[15];
  const float* W_wp    = (const float*)d_in[16];
  const float* b_wp    = (const float*)d_in[17];

  float* ws = (float*)d_ws;
  float* cmatA   = ws;               float* cmatB   = cmatA + RC;
  float* cmatC   = cmatB + RC;       float* cmatD   = cmatC + RC;
  float* matA    = cmatD + RC;       float* matB    = matA + RC;
  float* hstageC = matB + RC;        float* hstageD = hstageC + RC;
  float* hpC     = hstageD + RC;     float* hpD     = hpC + RC;
  float* projA   = hpD + RC;         float* projB   = projA + RC;
  float* matTA   = projB + RC;       float* matTB   = matTA + 256*MT;
  float* colA    = matTB + 256*MT;   float* colB    = colA + 256;
  float* wsumP   = colB + 256;       // 2*511*4*256
  float* esumP   = wsumP + 2*511*4*256;  // 2*511*4
  // total ~11.6 MB

  static const int offs[9] = {0, 256, 384, 448, 480, 496, 504, 508, 510};

  k_init<<<128, 256, 0, stream>>>(l_idx, r_idx, emb, W_ioux, b_ioux, b_iouh,
                                  cmatA, matA, cmatB, matB);
  for (int i = 1; i <= 8; ++i){
    int Nc = 256 >> i;
    k_levelAB<<<2*Nc, 512, 0, stream>>>(W_iouh, b_iouh, W_fh, b_fh,
                                        Nc, offs[i-1], offs[i],
                                        cmatA, matA, cmatB, matB);
  }
  k_mid<<<450, 256, 0, stream>>>(W_attnh, b_attnh, matA, matB,
                                 projA, projB, colA, colB, matTA, matTB,
                                 hpC, hpD);
  // scores for the 512 "level-0" rows of C and D
  k_scores<<<2*256*4, 256, 0, stream>>>(hpC, hpD, projA, projB, matTA, matTB,
                                        Wa, 256, 0, wsumP, esumP);
  for (int i = 1; i <= 8; ++i){
    int Nc = 256 >> i;
    const float* childHC = (i == 1) ? matB  : hstageC;  // C's h0 = pass-B rows
    const float* childHD = (i == 1) ? matA  : hstageD;
    const float* childCC = (i == 1) ? cmatB : cmatC;
    const float* childCD = (i == 1) ? cmatA : cmatD;
    k_cd1<<<2*Nc, 512, 0, stream>>>(W_iouh, b_iouh, W_fh, b_fh, W_attnh,
                                    Nc, offs[i-1], offs[i],
                                    colA, colB, wsumP, esumP,
                                    childHC, childHD, childCC, childCD,
                                    cmatC, cmatD, hstageC, hstageD, hpC, hpD);
    k_scores<<<2*Nc*4, 256, 0, stream>>>(hpC, hpD, projA, projB, matTA, matTB,
                                         Wa, Nc, offs[i], wsumP, esumP);
  }
  k_head<<<1, 256, 0, stream>>>(W_wh, b_wh, W_wp, b_wp, matA, matB,
                                colA, colB, wsumP, esumP, hstageC, hstageD,
                                (float*)d_out);
}

// Round 8
// 918.074 us; speedup vs baseline: 2.7793x; 1.0052x over previous
//
#include <hip/hip_runtime.h>

#define RC 130816   // 511*256
#define MT 512      // matT m-stride (511 zero-padded)

__device__ __forceinline__ float rcpf(float x){ return __builtin_amdgcn_rcpf(x); }
__device__ __forceinline__ float sigmf(float x){ return rcpf(1.f + __expf(-x)); }
__device__ __forceinline__ float tanhfast(float x){
  return 1.f - 2.f*rcpf(1.f + __expf(2.f*x));
}

// ---------------------------------------------------------------------------
// Init: block = (pass p, 4 rows); per-thread contiguous float4 W_ioux streams.
// ---------------------------------------------------------------------------
__global__ void __launch_bounds__(256) k_init(
    const int* __restrict__ l_idx, const int* __restrict__ r_idx,
    const float* __restrict__ emb, const float* __restrict__ W_ioux,
    const float* __restrict__ b_ioux, const float* __restrict__ b_iouh,
    float* __restrict__ cmatA, float* __restrict__ matA,
    float* __restrict__ cmatB, float* __restrict__ matB)
{
  int b = blockIdx.x, tid = threadIdx.x;
  int p = b>>6, n0 = (b&63)*4;
  __shared__ __align__(16) float xs[300*4];   // xs[d*4+rr]
  for (int j = tid; j < 4*300; j += 256){
    int rr = j/300, d = j - rr*300;
    int row = p ? r_idx[n0+rr] : l_idx[n0+rr];
    xs[d*4+rr] = emb[(size_t)row*300 + d];
  }
  __syncthreads();
  int t = tid;
  const float4* wi = (const float4*)(W_ioux + (size_t)t*300);
  const float4* wo = (const float4*)(W_ioux + (size_t)(t+256)*300);
  const float4* wu = (const float4*)(W_ioux + (size_t)(t+512)*300);
  float ai[4]={0,0,0,0}, ao[4]={0,0,0,0}, au[4]={0,0,0,0};
  #pragma unroll 3
  for (int k = 0; k < 75; ++k){
    float4 a = wi[k], o = wo[k], u = wu[k];
    const float4* xp = (const float4*)(xs + k*16);
    float4 x0 = xp[0], x1 = xp[1], x2 = xp[2], x3 = xp[3];
    ai[0]+=a.x*x0.x+a.y*x1.x+a.z*x2.x+a.w*x3.x;
    ai[1]+=a.x*x0.y+a.y*x1.y+a.z*x2.y+a.w*x3.y;
    ai[2]+=a.x*x0.z+a.y*x1.z+a.z*x2.z+a.w*x3.z;
    ai[3]+=a.x*x0.w+a.y*x1.w+a.z*x2.w+a.w*x3.w;
    ao[0]+=o.x*x0.x+o.y*x1.x+o.z*x2.x+o.w*x3.x;
    ao[1]+=o.x*x0.y+o.y*x1.y+o.z*x2.y+o.w*x3.y;
    ao[2]+=o.x*x0.z+o.y*x1.z+o.z*x2.z+o.w*x3.z;
    ao[3]+=o.x*x0.w+o.y*x1.w+o.z*x2.w+o.w*x3.w;
    au[0]+=u.x*x0.x+u.y*x1.x+u.z*x2.x+u.w*x3.x;
    au[1]+=u.x*x0.y+u.y*x1.y+u.z*x2.y+u.w*x3.y;
    au[2]+=u.x*x0.z+u.y*x1.z+u.z*x2.z+u.w*x3.z;
    au[3]+=u.x*x0.w+u.y*x1.w+u.z*x2.w+u.w*x3.w;
  }
  float* cmat = p ? cmatB : cmatA;
  float* hmat = p ? matB  : matA;
  float bi = b_ioux[t]     + b_iouh[t];
  float bo = b_ioux[256+t] + b_iouh[256+t];
  float bu = b_ioux[512+t] + b_iouh[512+t];
  #pragma unroll
  for (int rr = 0; rr < 4; ++rr){
    float c = sigmf(ai[rr]+bi)*tanhfast(au[rr]+bu);
    float h = sigmf(ao[rr]+bo)*tanhfast(c);
    cmat[(size_t)(n0+rr)*256 + t] = c;
    hmat[(size_t)(n0+rr)*256 + t] = h;
  }
}

// ---------------------------------------------------------------------------
// A/B tree level (no attention): block per output row, 512 threads.
// ---------------------------------------------------------------------------
__global__ void __launch_bounds__(512) k_levelAB(
    const float* __restrict__ W_iouh, const float* __restrict__ b_iouh,
    const float* __restrict__ W_fh, const float* __restrict__ b_fh,
    int Nc, int offPrev, int offCur,
    float* __restrict__ cmatA, float* __restrict__ matA,
    float* __restrict__ cmatB, float* __restrict__ matB)
{
  int b = blockIdx.x, tid = threadIdx.x;
  bool isA = (b < Nc); int n = isA ? b : b - Nc;
  float* cmat = isA ? cmatA : cmatB;
  float* hmat = isA ? matA  : matB;

  __shared__ __align__(16) float hs0[256], hs1[256], hss[256];
  __shared__ float sAu[256], sF0[256], sF1[256];
  const float* h0 = hmat + (size_t)(offPrev + 2*n)*256;
  const float* h1 = h0 + 256;
  const float* c0 = cmat + (size_t)(offPrev + 2*n)*256;
  const float* c1 = c0 + 256;
  if (tid < 256) hs0[tid] = h0[tid]; else hs1[tid-256] = h1[tid-256];
  __syncthreads();
  if (tid < 256) hss[tid] = hs0[tid] + hs1[tid];
  __syncthreads();

  float ai = 0.f, ao = 0.f;
  if (tid < 256){
    const float4* wi = (const float4*)(W_iouh + (size_t)tid*256);
    const float4* wo = (const float4*)(W_iouh + (size_t)(tid+256)*256);
    const float4* sv = (const float4*)hss;
    #pragma unroll 4
    for (int k = 0; k < 64; ++k){
      float4 a = wi[k], o = wo[k], s = sv[k];
      ai += a.x*s.x + a.y*s.y + a.z*s.z + a.w*s.w;
      ao += o.x*s.x + o.y*s.y + o.z*s.z + o.w*s.w;
    }
  } else {
    int u = tid - 256;
    const float4* wu = (const float4*)(W_iouh + (size_t)(u+512)*256);
    const float4* wf = (const float4*)(W_fh + (size_t)u*256);
    const float4* sv = (const float4*)hss;
    const float4* x0 = (const float4*)hs0;
    const float4* x1 = (const float4*)hs1;
    float au = 0.f, a0 = 0.f, a1 = 0.f;
    #pragma unroll 2
    for (int k = 0; k < 64; ++k){
      float4 uu = wu[k], ff = wf[k], s = sv[k], v0 = x0[k], v1 = x1[k];
      au += uu.x*s.x + uu.y*s.y + uu.z*s.z + uu.w*s.w;
      a0 += ff.x*v0.x + ff.y*v0.y + ff.z*v0.z + ff.w*v0.w;
      a1 += ff.x*v1.x + ff.y*v1.y + ff.z*v1.z + ff.w*v1.w;
    }
    sAu[u] = au; sF0[u] = a0; sF1[u] = a1;
  }
  __syncthreads();
  if (tid < 256){
    int t = tid;
    float i_ = sigmf(ai + b_iouh[t]);
    float o_ = sigmf(ao + b_iouh[256+t]);
    float u_ = tanhfast(sAu[t] + b_iouh[512+t]);
    float bf = b_fh[t];
    float c = i_*u_ + sigmf(sF0[t]+bf)*c0[t] + sigmf(sF1[t]+bf)*c1[t];
    float h = o_*tanhfast(c);
    cmat[(size_t)(offCur+n)*256 + t] = c;
    hmat[(size_t)(offCur+n)*256 + t] = h;
  }
}

// ---------------------------------------------------------------------------
// Mid: proj rows (0..127), colsums (128,129), matT transposes (130..385),
// hp for the 512 init rows of C/D (386..449).
// ---------------------------------------------------------------------------
__global__ void __launch_bounds__(256) k_mid(
    const float* __restrict__ W_attnh, const float* __restrict__ b_attnh,
    const float* __restrict__ matA, const float* __restrict__ matB,
    float* __restrict__ projA, float* __restrict__ projB,
    float* __restrict__ colA, float* __restrict__ colB,
    float* __restrict__ matTA, float* __restrict__ matTB,
    float* __restrict__ hpC, float* __restrict__ hpD)
{
  int b = blockIdx.x, tid = threadIdx.x;
  if (b < 128){
    int p = b>>6, ch = b&63, m0 = ch*8, mc = min(8, 511-m0);
    const float* mat = p ? matB : matA;
    float* proj = p ? projB : projA;
    __shared__ __align__(16) float ms[256*8];   // ms[e*8+rr]
    for (int j = tid; j < mc*256; j += 256){
      int rr = j>>8, e = j&255;
      ms[e*8+rr] = mat[(size_t)(m0+rr)*256 + e];
    }
    for (int j = tid + mc*256; j < 8*256; j += 256){
      int rr = j>>8, e = j&255; ms[e*8+rr] = 0.f;
    }
    __syncthreads();
    int t = tid;
    const float4* w2 = (const float4*)(W_attnh + (size_t)t*512 + 256);
    float acc[8] = {0,0,0,0,0,0,0,0};
    #pragma unroll 2
    for (int k = 0; k < 64; ++k){
      float4 w = w2[k];
      const float* base = ms + k*32;
      #pragma unroll
      for (int rr = 0; rr < 8; ++rr)
        acc[rr] += w.x*base[rr] + w.y*base[8+rr] + w.z*base[16+rr] + w.w*base[24+rr];
    }
    float ba = b_attnh[t];
    for (int rr = 0; rr < mc; ++rr) proj[(size_t)(m0+rr)*256 + t] = acc[rr] + ba;
  } else if (b < 130){
    int p = b - 128;
    const float* mat = p ? matB : matA;
    float* col = p ? colB : colA;
    float s = 0.f;
    #pragma unroll 8
    for (int m = 0; m < 511; ++m) s += mat[(size_t)m*256 + tid];
    col[tid] = s;
  } else if (b < 386){
    int idx = b - 130;
    int p = idx>>7, rem = idx&127, jt = rem>>4, mt = rem&15;
    const float* mat = p ? matB : matA;
    float* matT = p ? matTB : matTA;
    __shared__ float tile[32][33];
    int c = tid&31, r0 = tid>>5;
    int m0 = mt*32, j0 = jt*32;
    #pragma unroll
    for (int k = 0; k < 4; ++k){
      int m = m0 + r0 + 8*k;
      tile[r0+8*k][c] = (m < 511) ? mat[(size_t)m*256 + j0 + c] : 0.f;
    }
    __syncthreads();
    #pragma unroll
    for (int k = 0; k < 4; ++k){
      int jj = r0 + 8*k;
      matT[(size_t)(j0+jj)*MT + m0 + c] = tile[c][jj];
    }
  } else {
    int idx = b - 386;           // 64 blocks: p (C/D) x 32 chunks of 8 rows
    int p = idx>>5, ch = idx&31, r0 = ch*8;
    const float* hsrc = p ? matA : matB;   // C<-B, D<-A
    float* hp = p ? hpD : hpC;
    __shared__ __align__(16) float ms[256*8];
    for (int j = tid; j < 8*256; j += 256){
      int rr = j>>8, e = j&255;
      ms[e*8+rr] = hsrc[(size_t)(r0+rr)*256 + e];
    }
    __syncthreads();
    int t = tid;
    const float4* w1 = (const float4*)(W_attnh + (size_t)t*512);
    float acc[8] = {0,0,0,0,0,0,0,0};
    #pragma unroll 2
    for (int k = 0; k < 64; ++k){
      float4 w = w1[k];
      const float* base = ms + k*32;
      #pragma unroll
      for (int rr = 0; rr < 8; ++rr)
        acc[rr] += w.x*base[rr] + w.y*base[8+rr] + w.z*base[16+rr] + w.w*base[24+rr];
    }
    #pragma unroll
    for (int rr = 0; rr < 8; ++rr) hp[(size_t)(r0+rr)*256 + t] = acc[rr];
  }
}

// ---------------------------------------------------------------------------
// Tiled scores: block = (pass, G-row group, m-chunk of 128). 256 threads =
// 128 m x 2 d-halves. proj/matT streamed once per block, reused across G rows.
// Writes unnormalized wsumP[p][row][ch][256] and esumP[p][row][ch].
// ---------------------------------------------------------------------------
template<int G>
__global__ void __launch_bounds__(256) k_scores_t(
    const float* __restrict__ hpC, const float* __restrict__ hpD,
    const float* __restrict__ projA, const float* __restrict__ projB,
    const float* __restrict__ matTA, const float* __restrict__ matTB,
    const float* __restrict__ Wa, int Nc, int rowOff,
    float* __restrict__ wsumP, float* __restrict__ esumP)
{
  int b = blockIdx.x, tid = threadIdx.x;
  int groups = Nc / G;
  int per = groups * 4;
  int p = b / per; int rem = b - p*per; int g = rem >> 2, ch = rem & 3;
  int row0 = rowOff + g*G;
  const float* hp   = p ? hpD : hpC;
  const float* proj = p ? projB : projA;
  const float* matT = p ? matTB : matTA;

  __shared__ __align__(16) float shp[G*256];
  __shared__ __align__(16) float swa[256];
  __shared__ __align__(16) float spart[G*256];
  __shared__ __align__(16) float se[G*128];

  for (int j = tid; j < G*256; j += 256)
    shp[j] = hp[(size_t)(row0 + (j>>8))*256 + (j&255)];
  swa[tid] = Wa[tid];
  __syncthreads();

  int ml = tid & 127, dh = tid >> 7;
  int m = ch*128 + ml;
  float part[G];
  #pragma unroll
  for (int r = 0; r < G; ++r) part[r] = 0.f;
  if (m < 511){
    const float4* pr  = (const float4*)(proj + (size_t)m*256 + dh*128);
    const float4* wa4 = (const float4*)(swa + dh*128);
    #pragma unroll 4
    for (int k = 0; k < 32; ++k){
      float4 pv = pr[k], wv = wa4[k];
      int dbase = dh*128 + k*4;
      #pragma unroll
      for (int r = 0; r < G; ++r){
        const float* hr = shp + r*256 + dbase;
        part[r] += wv.x*tanhfast(hr[0]+pv.x) + wv.y*tanhfast(hr[1]+pv.y)
                 + wv.z*tanhfast(hr[2]+pv.z) + wv.w*tanhfast(hr[3]+pv.w);
      }
    }
  }
  #pragma unroll
  for (int r = 0; r < G; ++r) spart[r*256 + tid] = part[r];
  __syncthreads();
  if (tid < 128){
    #pragma unroll
    for (int r = 0; r < G; ++r){
      float s = spart[r*256 + ml] + spart[r*256 + 128 + ml];
      se[r*128 + ml] = (ch*128 + ml < 511) ? __expf(s) : 0.f;
    }
  }
  __syncthreads();
  // unnormalized weighted sums (matT pad row m=511 is zero)
  {
    const float4* mt = (const float4*)(matT + (size_t)tid*MT + ch*128);
    float acc[G];
    #pragma unroll
    for (int r = 0; r < G; ++r) acc[r] = 0.f;
    #pragma unroll 4
    for (int k = 0; k < 32; ++k){
      float4 mv = mt[k];
      #pragma unroll
      for (int r = 0; r < G; ++r){
        float4 ev = ((const float4*)(se + r*128))[k];
        acc[r] += mv.x*ev.x + mv.y*ev.y + mv.z*ev.z + mv.w*ev.w;
      }
    }
    #pragma unroll
    for (int r = 0; r < G; ++r)
      wsumP[(((size_t)p*511 + row0 + r)*4 + ch)*256 + tid] = acc[r];
  }
  if (tid < G){
    float s = 0.f;
    const float* sr = se + tid*128;
    for (int k = 0; k < 128; ++k) s += sr[k];
    esumP[((size_t)p*511 + row0 + tid)*4 + ch] = s;
  }
}

// ---------------------------------------------------------------------------
// CD spine: finish children's attend from partials, LSTM, h_pre + hp out.
// Block per output row (C then D), 512 threads.
// ---------------------------------------------------------------------------
__global__ void __launch_bounds__(512) k_cd1(
    const float* __restrict__ W_iouh, const float* __restrict__ b_iouh,
    const float* __restrict__ W_fh, const float* __restrict__ b_fh,
    const float* __restrict__ W_attnh,
    int Nc, int offPrev, int offCur,
    const float* __restrict__ colA, const float* __restrict__ colB,
    const float* __restrict__ wsumP, const float* __restrict__ esumP,
    const float* __restrict__ childHC, const float* __restrict__ childHD,
    const float* __restrict__ childCC, const float* __restrict__ childCD_,
    float* __restrict__ cmatC, float* __restrict__ cmatD,
    float* __restrict__ hstageC, float* __restrict__ hstageD,
    float* __restrict__ hpC, float* __restrict__ hpD)
{
  int b = blockIdx.x, tid = threadIdx.x;
  bool isC = (b < Nc); int n = isC ? b : b - Nc;
  int p = isC ? 0 : 1;
  const float* col    = isC ? colA : colB;
  const float* childH = isC ? childHC : childHD;
  const float* childC = isC ? childCC : childCD_;
  float* cmat   = isC ? cmatC : cmatD;
  float* hstage = isC ? hstageC : hstageD;
  float* hpbuf  = isC ? hpC : hpD;

  __shared__ __align__(16) float hs0[256], hs1[256], hss[256];
  __shared__ float sAu[256], sF0[256], sF1[256];
  __shared__ __align__(16) float shh[256], php[512];

  // finish attend of the two children rows
  {
    int ch = tid >> 8, j = tid & 255;
    int r = offPrev + 2*n + ch;
    const float* wp = wsumP + (((size_t)p*511 + r)*4)*256;
    float w = wp[j] + wp[256+j] + wp[512+j] + wp[768+j];
    const float* ep = esumP + ((size_t)p*511 + r)*4;
    float esum = ep[0]+ep[1]+ep[2]+ep[3];
    float hatt = col[j] - w*rcpf(esum) + childH[(size_t)r*256 + j];
    if (ch) hs1[j] = hatt; else hs0[j] = hatt;
  }
  __syncthreads();
  if (tid < 256) hss[tid] = hs0[tid] + hs1[tid];
  __syncthreads();

  const float* c0 = childC + (size_t)(offPrev + 2*n)*256;
  const float* c1 = c0 + 256;
  float ai = 0.f, ao = 0.f;
  if (tid < 256){
    const float4* wi = (const float4*)(W_iouh + (size_t)tid*256);
    const float4* wo = (const float4*)(W_iouh + (size_t)(tid+256)*256);
    const float4* sv = (const float4*)hss;
    #pragma unroll 4
    for (int k = 0; k < 64; ++k){
      float4 a = wi[k], o = wo[k], s = sv[k];
      ai += a.x*s.x + a.y*s.y + a.z*s.z + a.w*s.w;
      ao += o.x*s.x + o.y*s.y + o.z*s.z + o.w*s.w;
    }
  } else {
    int u = tid - 256;
    const float4* wu = (const float4*)(W_iouh + (size_t)(u+512)*256);
    const float4* wf = (const float4*)(W_fh + (size_t)u*256);
    const float4* sv = (const float4*)hss;
    const float4* x0 = (const float4*)hs0;
    const float4* x1 = (const float4*)hs1;
    float au = 0.f, a0 = 0.f, a1 = 0.f;
    #pragma unroll 2
    for (int k = 0; k < 64; ++k){
      float4 uu = wu[k], ff = wf[k], s = sv[k], v0 = x0[k], v1 = x1[k];
      au += uu.x*s.x + uu.y*s.y + uu.z*s.z + uu.w*s.w;
      a0 += ff.x*v0.x + ff.y*v0.y + ff.z*v0.z + ff.w*v0.w;
      a1 += ff.x*v1.x + ff.y*v1.y + ff.z*v1.z + ff.w*v1.w;
    }
    sAu[u] = au; sF0[u] = a0; sF1[u] = a1;
  }
  __syncthreads();
  if (tid < 256){
    int t = tid;
    float i_ = sigmf(ai + b_iouh[t]);
    float o_ = sigmf(ao + b_iouh[256+t]);
    float u_ = tanhfast(sAu[t] + b_iouh[512+t]);
    float bf = b_fh[t];
    float c = i_*u_ + sigmf(sF0[t]+bf)*c0[t] + sigmf(sF1[t]+bf)*c1[t];
    float h = o_*tanhfast(c);
    cmat[(size_t)(offCur+n)*256 + t] = c;
    hstage[(size_t)(offCur+n)*256 + t] = h;
    shh[t] = h;
  }
  __syncthreads();
  // hp = h_pre @ W1^T (split e-range across the two thread groups)
  {
    int g = tid>>8, j = tid&255;
    const float4* w = (const float4*)(W_attnh + (size_t)j*512 + g*128);
    const float4* hh = (const float4*)(shh + g*128);
    float a = 0.f;
    #pragma unroll 4
    for (int k = 0; k < 32; ++k){
      float4 wv = w[k], hv = hh[k];
      a += wv.x*hv.x + wv.y*hv.y + wv.z*hv.z + wv.w*hv.w;
    }
    php[g*256 + j] = a;
  }
  __syncthreads();
  if (tid < 256) hpbuf[(size_t)(offCur+n)*256 + tid] = php[tid] + php[256+tid];
}

// ---------------------------------------------------------------------------
// Head: finish row 510 of C and D, then MLP + log_softmax. 1 block x 256.
// ---------------------------------------------------------------------------
__global__ void __launch_bounds__(256) k_head(
    const float* __restrict__ W_wh, const float* __restrict__ b_wh,
    const float* __restrict__ W_wp, const float* __restrict__ b_wp,
    const float* __restrict__ matA, const float* __restrict__ matB,
    const float* __restrict__ colA, const float* __restrict__ colB,
    const float* __restrict__ wsumP, const float* __restrict__ esumP,
    const float* __restrict__ hstageC, const float* __restrict__ hstageD,
    float* __restrict__ out)
{
  __shared__ __align__(16) float v[512];
  __shared__ float og[128], lg[5];
  int t = threadIdx.x;
  {
    const float* wpC = wsumP + (((size_t)0*511 + 510)*4)*256;
    const float* epC = esumP + ((size_t)0*511 + 510)*4;
    float wC = wpC[t] + wpC[256+t] + wpC[512+t] + wpC[768+t];
    float eC = epC[0]+epC[1]+epC[2]+epC[3];
    float hCf = colA[t] - wC*rcpf(eC) + hstageC[(size_t)510*256 + t];
    const float* wpD = wsumP + (((size_t)1*511 + 510)*4)*256;
    const float* epD = esumP + ((size_t)1*511 + 510)*4;
    float wD = wpD[t] + wpD[256+t] + wpD[512+t] + wpD[768+t];
    float eD = epD[0]+epD[1]+epD[2]+epD[3];
    float hDf = colB[t] - wD*rcpf(eD) + hstageD[(size_t)510*256 + t];
    float lh = tanhfast(matA[(size_t)510*256 + t] + hDf);
    float rh = tanhfast(hCf + matB[(size_t)510*256 + t]);
    v[t] = lh*rh;
    v[256+t] = fabsf(lh - rh);
  }
  __syncthreads();
  if (t < 128){
    const float4* w = (const float4*)(W_wh + (size_t)t*512);
    const float4* vv = (const float4*)v;
    float a = b_wh[t];
    #pragma unroll 4
    for (int k = 0; k < 128; ++k){
      float4 wv = w[k], x = vv[k];
      a += wv.x*x.x + wv.y*x.y + wv.z*x.z + wv.w*x.w;
    }
    og[t] = sigmf(a);
  }
  __syncthreads();
  if (t < 5){
    const float* wp = W_wp + (size_t)t*128;
    float a = b_wp[t];
    for (int j = 0; j < 128; ++j) a += og[j]*wp[j];
    lg[t] = a;
  }
  __syncthreads();
  if (t == 0){
    float M = -1e30f;
    for (int c = 0; c < 5; ++c) M = fmaxf(M, lg[c]);
    float S = 0.f;
    for (int c = 0; c < 5; ++c) S += __expf(lg[c] - M);
    float L = logf(S);
    for (int c = 0; c < 5; ++c) out[c] = lg[c] - M - L;
  }
}

extern "C" void kernel_launch(void* const* d_in, const int* in_sizes, int n_in,
                              void* d_out, int out_size, void* d_ws, size_t ws_size,
                              hipStream_t stream)
{
  const int*   l_idx   = (const int*)  d_in[0];
  const int*   r_idx   = (const int*)  d_in[1];
  const float* emb     = (const float*)d_in[2];
  const float* W_ioux  = (const float*)d_in[3];
  const float* b_ioux  = (const float*)d_in[4];
  const float* W_iouh  = (const float*)d_in[5];
  const float* b_iouh  = (const float*)d_in[6];
  // d_in[7]=W_fx, d_in[8]=b_fx unused by the forward
  const float* W_fh    = (const float*)d_in[9];
  const float* b_fh    = (const float*)d_in[10];
  const float* Wa      = (const float*)d_in[11];
  const float* W_attnh = (const float*)d_in[12];
  const float* b_attnh = (const float*)d_in[13];
  const float* W_wh    = (const float*)d_in[14];
  const float* b_wh    = (const float*)d_in[15];
  const float* W_wp    = (const float*)d_in[16];
  const float* b_wp    = (const float*)d_in[17];

  float* ws = (float*)d_ws;
  float* cmatA   = ws;               float* cmatB   = cmatA + RC;
  float* cmatC   = cmatB + RC;       float* cmatD   = cmatC + RC;
  float* matA    = cmatD + RC;       float* matB    = matA + RC;
  float* hstageC = matB + RC;        float* hstageD = hstageC + RC;
  float* hpC     = hstageD + RC;     float* hpD     = hpC + RC;
  float* projA   = hpD + RC;         float* projB   = projA + RC;
  float* matTA   = projB + RC;       float* matTB   = matTA + 256*MT;
  float* colA    = matTB + 256*MT;   float* colB    = colA + 256;
  float* wsumP   = colB + 256;            // 2*511*4*256
  float* esumP   = wsumP + 2*511*4*256;   // 2*511*4
  // total ~11.6 MB

  static const int offs[9] = {0, 256, 384, 448, 480, 496, 504, 508, 510};

  k_init<<<128, 256, 0, stream>>>(l_idx, r_idx, emb, W_ioux, b_ioux, b_iouh,
                                  cmatA, matA, cmatB, matB);
  for (int i = 1; i <= 8; ++i){
    int Nc = 256 >> i;
    k_levelAB<<<2*Nc, 512, 0, stream>>>(W_iouh, b_iouh, W_fh, b_fh,
                                        Nc, offs[i-1], offs[i],
                                        cmatA, matA, cmatB, matB);
  }
  k_mid<<<450, 256, 0, stream>>>(W_attnh, b_attnh, matA, matB,
                                 projA, projB, colA, colB, matTA, matTB,
                                 hpC, hpD);
  // scores for the 512 "level-0" rows of C and D (G=4)
  k_scores_t<4><<<2*(256/4)*4, 256, 0, stream>>>(hpC, hpD, projA, projB,
                                                 matTA, matTB, Wa, 256, 0,
                                                 wsumP, esumP);
  for (int i = 1; i <= 8; ++i){
    int Nc = 256 >> i;
    const float* childHC = (i == 1) ? matB  : hstageC;  // C's h0 = pass-B rows
    const float* childHD = (i == 1) ? matA  : hstageD;
    const float* childCC = (i == 1) ? cmatB : cmatC;
    const float* childCD = (i == 1) ? cmatA : cmatD;
    k_cd1<<<2*Nc, 512, 0, stream>>>(W_iouh, b_iouh, W_fh, b_fh, W_attnh,
                                    Nc, offs[i-1], offs[i],
                                    colA, colB, wsumP, esumP,
                                    childHC, childHD, childCC, childCD,
                                    cmatC, cmatD, hstageC, hstageD, hpC, hpD);
    if (Nc >= 4)
      k_scores_t<4><<<2*(Nc/4)*4, 256, 0, stream>>>(hpC, hpD, projA, projB,
                                                    matTA, matTB, Wa, Nc, offs[i],
                                                    wsumP, esumP);
    else if (Nc == 2)
      k_scores_t<2><<<2*(Nc/2)*4, 256, 0, stream>>>(hpC, hpD, projA, projB,
                                                    matTA, matTB, Wa, Nc, offs[i],
                                                    wsumP, esumP);
    else
      k_scores_t<1><<<2*Nc*4, 256, 0, stream>>>(hpC, hpD, projA, projB,
                                                matTA, matTB, Wa, Nc, offs[i],
                                                wsumP, esumP);
  }
  k_head<<<1, 256, 0, stream>>>(W_wh, b_wh, W_wp, b_wp, matA, matB,
                                colA, colB, wsumP, esumP, hstageC, hstageD,
                                (float*)d_out);
}

// Round 9
// 668.561 us; speedup vs baseline: 3.8165x; 1.3732x over previous
//
#include <hip/hip_runtime.h>

#define RC 130816   // 511*256
#define MT 512      // matT m-stride (511 zero-padded)

// bf16 weight cache layout (ushort offsets)
#define B16_IOUH 0        // 768*256
#define B16_FH   196608   // 256*256
#define B16_W1   262144   // 256*256 (W_attnh[:, :256])
#define B16_TOT  327680

__device__ __forceinline__ float rcpf(float x){ return __builtin_amdgcn_rcpf(x); }
__device__ __forceinline__ float sigmf(float x){ return rcpf(1.f + __expf(-x)); }
__device__ __forceinline__ float tanhfast(float x){
  return 1.f - 2.f*rcpf(1.f + __expf(2.f*x));
}

// ---- bf16-as-integer helpers (no fp16/bf16 intrinsics) ----
__device__ __forceinline__ float bfl(unsigned x){ return __uint_as_float(x << 16); }
__device__ __forceinline__ float bfh(unsigned x){ return __uint_as_float(x & 0xFFFF0000u); }
__device__ __forceinline__ unsigned bpack(float a, float b){
  unsigned ua = __float_as_uint(a), ub = __float_as_uint(b);
  return ((ua + 0x7FFFu + ((ua>>16)&1u)) >> 16)
       | ((ub + 0x7FFFu + ((ub>>16)&1u)) & 0xFFFF0000u);
}
// dot of 8 bf16 weights (one uint4) with 8 fp32 values (two float4s)
__device__ __forceinline__ float dot8b(uint4 w, const float4* s4){
  float4 s0 = s4[0], s1 = s4[1];
  return bfl(w.x)*s0.x + bfh(w.x)*s0.y + bfl(w.y)*s0.z + bfh(w.y)*s0.w
       + bfl(w.z)*s1.x + bfh(w.z)*s1.y + bfl(w.w)*s1.z + bfh(w.w)*s1.w;
}

// ---------------------------------------------------------------------------
// Pack W_iouh / W_fh / W1 (=W_attnh[:,:256]) to bf16. Grid-stride, uint out.
// ---------------------------------------------------------------------------
__global__ void __launch_bounds__(256) k_pack(
    const float* __restrict__ W_iouh, const float* __restrict__ W_fh,
    const float* __restrict__ W_attnh, unsigned* __restrict__ W16u)
{
  int g0 = blockIdx.x*blockDim.x + threadIdx.x, gs = gridDim.x*blockDim.x;
  for (int k = g0; k < 98304; k += gs){
    int i = 2*k; W16u[k] = bpack(W_iouh[i], W_iouh[i+1]);
  }
  for (int k = g0; k < 32768; k += gs){
    int i = 2*k; W16u[98304 + k] = bpack(W_fh[i], W_fh[i+1]);
  }
  for (int k = g0; k < 32768; k += gs){
    int i = 2*k; int t = i>>8, e = i&255;
    const float* r = W_attnh + (size_t)t*512;
    W16u[131072 + k] = bpack(r[e], r[e+1]);
  }
}

// ---------------------------------------------------------------------------
// Init v2: 256 blocks x 768 threads; block = (pass p, 2 rows). Thread tid
// computes gate-column tid (one 300-float W_ioux row, 75 float4s) for both
// rows; gates recombined via LDS.
// ---------------------------------------------------------------------------
__global__ void __launch_bounds__(768) k_init(
    const int* __restrict__ l_idx, const int* __restrict__ r_idx,
    const float* __restrict__ emb, const float* __restrict__ W_ioux,
    const float* __restrict__ b_ioux, const float* __restrict__ b_iouh,
    float* __restrict__ cmatA, float* __restrict__ matA,
    float* __restrict__ cmatB, float* __restrict__ matB)
{
  int b = blockIdx.x, tid = threadIdx.x;
  int p = b >> 7, n0 = (b & 127) * 2;
  __shared__ __align__(16) float xs[2*304];
  __shared__ float sg[2*768];
  for (int j = tid; j < 600; j += 768){
    int rr = j/300, d = j - rr*300;
    int row = p ? r_idx[n0+rr] : l_idx[n0+rr];
    xs[rr*304 + d] = emb[(size_t)row*300 + d];
  }
  __syncthreads();
  const float4* w = (const float4*)(W_ioux + (size_t)tid*300);
  float a0 = 0.f, a1 = 0.f;
  #pragma unroll 5
  for (int k = 0; k < 75; ++k){
    float4 wv = w[k];
    const float* x0 = xs + 4*k;
    const float* x1 = xs + 304 + 4*k;
    a0 += wv.x*x0[0] + wv.y*x0[1] + wv.z*x0[2] + wv.w*x0[3];
    a1 += wv.x*x1[0] + wv.y*x1[1] + wv.z*x1[2] + wv.w*x1[3];
  }
  float bb = b_ioux[tid] + b_iouh[tid];
  sg[tid] = a0 + bb;
  sg[768 + tid] = a1 + bb;
  __syncthreads();
  if (tid < 512){
    int rr = tid >> 8, t = tid & 255;
    const float* g = sg + rr*768;
    float c = sigmf(g[t]) * tanhfast(g[512+t]);
    float h = sigmf(g[256+t]) * tanhfast(c);
    (p ? cmatB : cmatA)[(size_t)(n0+rr)*256 + t] = c;
    (p ? matB  : matA )[(size_t)(n0+rr)*256 + t] = h;
  }
}

// ---------------------------------------------------------------------------
// A/B tree level (no attention): block per output row, 512 threads, bf16 W.
// ---------------------------------------------------------------------------
__global__ void __launch_bounds__(512) k_levelAB(
    const unsigned short* __restrict__ W16, const float* __restrict__ b_iouh,
    const float* __restrict__ b_fh,
    int Nc, int offPrev, int offCur,
    float* __restrict__ cmatA, float* __restrict__ matA,
    float* __restrict__ cmatB, float* __restrict__ matB)
{
  int b = blockIdx.x, tid = threadIdx.x;
  bool isA = (b < Nc); int n = isA ? b : b - Nc;
  float* cmat = isA ? cmatA : cmatB;
  float* hmat = isA ? matA  : matB;

  __shared__ __align__(16) float hs0[256], hs1[256], hss[256];
  __shared__ float sAu[256], sF0[256], sF1[256];
  const float* h0 = hmat + (size_t)(offPrev + 2*n)*256;
  const float* h1 = h0 + 256;
  const float* c0 = cmat + (size_t)(offPrev + 2*n)*256;
  const float* c1 = c0 + 256;
  if (tid < 256) hs0[tid] = h0[tid]; else hs1[tid-256] = h1[tid-256];
  __syncthreads();
  if (tid < 256) hss[tid] = hs0[tid] + hs1[tid];
  __syncthreads();

  float ai = 0.f, ao = 0.f;
  if (tid < 256){
    const uint4* wi = (const uint4*)(W16 + (size_t)tid*256);
    const uint4* wo = (const uint4*)(W16 + (size_t)(tid+256)*256);
    const float4* sv = (const float4*)hss;
    #pragma unroll 4
    for (int k = 0; k < 32; ++k){
      ai += dot8b(wi[k], sv + 2*k);
      ao += dot8b(wo[k], sv + 2*k);
    }
  } else {
    int u = tid - 256;
    const uint4* wu = (const uint4*)(W16 + (size_t)(u+512)*256);
    const uint4* wf = (const uint4*)(W16 + B16_FH + (size_t)u*256);
    const float4* sv = (const float4*)hss;
    const float4* x0 = (const float4*)hs0;
    const float4* x1 = (const float4*)hs1;
    float au = 0.f, a0 = 0.f, a1 = 0.f;
    #pragma unroll 4
    for (int k = 0; k < 32; ++k){
      au += dot8b(wu[k], sv + 2*k);
      uint4 fv = wf[k];
      a0 += dot8b(fv, x0 + 2*k);
      a1 += dot8b(fv, x1 + 2*k);
    }
    sAu[u] = au; sF0[u] = a0; sF1[u] = a1;
  }
  __syncthreads();
  if (tid < 256){
    int t = tid;
    float i_ = sigmf(ai + b_iouh[t]);
    float o_ = sigmf(ao + b_iouh[256+t]);
    float u_ = tanhfast(sAu[t] + b_iouh[512+t]);
    float bf = b_fh[t];
    float c = i_*u_ + sigmf(sF0[t]+bf)*c0[t] + sigmf(sF1[t]+bf)*c1[t];
    float h = o_*tanhfast(c);
    cmat[(size_t)(offCur+n)*256 + t] = c;
    hmat[(size_t)(offCur+n)*256 + t] = h;
  }
}

// ---------------------------------------------------------------------------
// Mid: proj rows (0..127), colsums (128,129), matT transposes (130..385),
// hp for the 512 init rows of C/D (386..449). fp32 (runs once).
// ---------------------------------------------------------------------------
__global__ void __launch_bounds__(256) k_mid(
    const float* __restrict__ W_attnh, const float* __restrict__ b_attnh,
    const float* __restrict__ matA, const float* __restrict__ matB,
    float* __restrict__ projA, float* __restrict__ projB,
    float* __restrict__ colA, float* __restrict__ colB,
    float* __restrict__ matTA, float* __restrict__ matTB,
    float* __restrict__ hpC, float* __restrict__ hpD)
{
  int b = blockIdx.x, tid = threadIdx.x;
  if (b < 128){
    int p = b>>6, ch = b&63, m0 = ch*8, mc = min(8, 511-m0);
    const float* mat = p ? matB : matA;
    float* proj = p ? projB : projA;
    __shared__ __align__(16) float ms[256*8];   // ms[e*8+rr]
    for (int j = tid; j < mc*256; j += 256){
      int rr = j>>8, e = j&255;
      ms[e*8+rr] = mat[(size_t)(m0+rr)*256 + e];
    }
    for (int j = tid + mc*256; j < 8*256; j += 256){
      int rr = j>>8, e = j&255; ms[e*8+rr] = 0.f;
    }
    __syncthreads();
    int t = tid;
    const float4* w2 = (const float4*)(W_attnh + (size_t)t*512 + 256);
    float acc[8] = {0,0,0,0,0,0,0,0};
    #pragma unroll 2
    for (int k = 0; k < 64; ++k){
      float4 w = w2[k];
      const float* base = ms + k*32;
      #pragma unroll
      for (int rr = 0; rr < 8; ++rr)
        acc[rr] += w.x*base[rr] + w.y*base[8+rr] + w.z*base[16+rr] + w.w*base[24+rr];
    }
    float ba = b_attnh[t];
    for (int rr = 0; rr < mc; ++rr) proj[(size_t)(m0+rr)*256 + t] = acc[rr] + ba;
  } else if (b < 130){
    int p = b - 128;
    const float* mat = p ? matB : matA;
    float* col = p ? colB : colA;
    float s = 0.f;
    #pragma unroll 8
    for (int m = 0; m < 511; ++m) s += mat[(size_t)m*256 + tid];
    col[tid] = s;
  } else if (b < 386){
    int idx = b - 130;
    int p = idx>>7, rem = idx&127, jt = rem>>4, mt = rem&15;
    const float* mat = p ? matB : matA;
    float* matT = p ? matTB : matTA;
    __shared__ float tile[32][33];
    int c = tid&31, r0 = tid>>5;
    int m0 = mt*32, j0 = jt*32;
    #pragma unroll
    for (int k = 0; k < 4; ++k){
      int m = m0 + r0 + 8*k;
      tile[r0+8*k][c] = (m < 511) ? mat[(size_t)m*256 + j0 + c] : 0.f;
    }
    __syncthreads();
    #pragma unroll
    for (int k = 0; k < 4; ++k){
      int jj = r0 + 8*k;
      matT[(size_t)(j0+jj)*MT + m0 + c] = tile[c][jj];
    }
  } else {
    int idx = b - 386;           // 64 blocks: p (C/D) x 32 chunks of 8 rows
    int p = idx>>5, ch = idx&31, r0 = ch*8;
    const float* hsrc = p ? matA : matB;   // C<-B, D<-A
    float* hp = p ? hpD : hpC;
    __shared__ __align__(16) float ms[256*8];
    for (int j = tid; j < 8*256; j += 256){
      int rr = j>>8, e = j&255;
      ms[e*8+rr] = hsrc[(size_t)(r0+rr)*256 + e];
    }
    __syncthreads();
    int t = tid;
    const float4* w1 = (const float4*)(W_attnh + (size_t)t*512);
    float acc[8] = {0,0,0,0,0,0,0,0};
    #pragma unroll 2
    for (int k = 0; k < 64; ++k){
      float4 w = w1[k];
      const float* base = ms + k*32;
      #pragma unroll
      for (int rr = 0; rr < 8; ++rr)
        acc[rr] += w.x*base[rr] + w.y*base[8+rr] + w.z*base[16+rr] + w.w*base[24+rr];
    }
    #pragma unroll
    for (int rr = 0; rr < 8; ++rr) hp[(size_t)(r0+rr)*256 + t] = acc[rr];
  }
}

// ---------------------------------------------------------------------------
// Tiled scores: block = (pass, G-row group, m-chunk of 128). 256 threads =
// 128 m x 2 d-halves. proj/matT streamed once per block, reused across G rows.
// ---------------------------------------------------------------------------
template<int G>
__global__ void __launch_bounds__(256) k_scores_t(
    const float* __restrict__ hpC, const float* __restrict__ hpD,
    const float* __restrict__ projA, const float* __restrict__ projB,
    const float* __restrict__ matTA, const float* __restrict__ matTB,
    const float* __restrict__ Wa, int Nc, int rowOff,
    float* __restrict__ wsumP, float* __restrict__ esumP)
{
  int b = blockIdx.x, tid = threadIdx.x;
  int groups = Nc / G;
  int per = groups * 4;
  int p = b / per; int rem = b - p*per; int g = rem >> 2, ch = rem & 3;
  int row0 = rowOff + g*G;
  const float* hp   = p ? hpD : hpC;
  const float* proj = p ? projB : projA;
  const float* matT = p ? matTB : matTA;

  __shared__ __align__(16) float shp[G*256];
  __shared__ __align__(16) float swa[256];
  __shared__ __align__(16) float spart[G*256];
  __shared__ __align__(16) float se[G*128];

  for (int j = tid; j < G*256; j += 256)
    shp[j] = hp[(size_t)(row0 + (j>>8))*256 + (j&255)];
  swa[tid] = Wa[tid];
  __syncthreads();

  int ml = tid & 127, dh = tid >> 7;
  int m = ch*128 + ml;
  float part[G];
  #pragma unroll
  for (int r = 0; r < G; ++r) part[r] = 0.f;
  if (m < 511){
    const float4* pr  = (const float4*)(proj + (size_t)m*256 + dh*128);
    const float4* wa4 = (const float4*)(swa + dh*128);
    #pragma unroll 4
    for (int k = 0; k < 32; ++k){
      float4 pv = pr[k], wv = wa4[k];
      int dbase = dh*128 + k*4;
      #pragma unroll
      for (int r = 0; r < G; ++r){
        const float* hr = shp + r*256 + dbase;
        part[r] += wv.x*tanhfast(hr[0]+pv.x) + wv.y*tanhfast(hr[1]+pv.y)
                 + wv.z*tanhfast(hr[2]+pv.z) + wv.w*tanhfast(hr[3]+pv.w);
      }
    }
  }
  #pragma unroll
  for (int r = 0; r < G; ++r) spart[r*256 + tid] = part[r];
  __syncthreads();
  if (tid < 128){
    #pragma unroll
    for (int r = 0; r < G; ++r){
      float s = spart[r*256 + ml] + spart[r*256 + 128 + ml];
      se[r*128 + ml] = (ch*128 + ml < 511) ? __expf(s) : 0.f;
    }
  }
  __syncthreads();
  {
    const float4* mt = (const float4*)(matT + (size_t)tid*MT + ch*128);
    float acc[G];
    #pragma unroll
    for (int r = 0; r < G; ++r) acc[r] = 0.f;
    #pragma unroll 4
    for (int k = 0; k < 32; ++k){
      float4 mv = mt[k];
      #pragma unroll
      for (int r = 0; r < G; ++r){
        float4 ev = ((const float4*)(se + r*128))[k];
        acc[r] += mv.x*ev.x + mv.y*ev.y + mv.z*ev.z + mv.w*ev.w;
      }
    }
    #pragma unroll
    for (int r = 0; r < G; ++r)
      wsumP[(((size_t)p*511 + row0 + r)*4 + ch)*256 + tid] = acc[r];
  }
  if (tid < G){
    float s = 0.f;
    const float* sr = se + tid*128;
    for (int k = 0; k < 128; ++k) s += sr[k];
    esumP[((size_t)p*511 + row0 + tid)*4 + ch] = s;
  }
}

// ---------------------------------------------------------------------------
// CD spine: finish children's attend from partials, LSTM (bf16 W), h_pre + hp.
// Block per output row (C then D), 512 threads.
// ---------------------------------------------------------------------------
__global__ void __launch_bounds__(512) k_cd1(
    const unsigned short* __restrict__ W16, const float* __restrict__ b_iouh,
    const float* __restrict__ b_fh,
    int Nc, int offPrev, int offCur,
    const float* __restrict__ colA, const float* __restrict__ colB,
    const float* __restrict__ wsumP, const float* __restrict__ esumP,
    const float* __restrict__ childHC, const float* __restrict__ childHD,
    const float* __restrict__ childCC, const float* __restrict__ childCD_,
    float* __restrict__ cmatC, float* __restrict__ cmatD,
    float* __restrict__ hstageC, float* __restrict__ hstageD,
    float* __restrict__ hpC, float* __restrict__ hpD)
{
  int b = blockIdx.x, tid = threadIdx.x;
  bool isC = (b < Nc); int n = isC ? b : b - Nc;
  int p = isC ? 0 : 1;
  const float* col    = isC ? colA : colB;
  const float* childH = isC ? childHC : childHD;
  const float* childC = isC ? childCC : childCD_;
  float* cmat   = isC ? cmatC : cmatD;
  float* hstage = isC ? hstageC : hstageD;
  float* hpbuf  = isC ? hpC : hpD;

  __shared__ __align__(16) float hs0[256], hs1[256], hss[256];
  __shared__ float sAu[256], sF0[256], sF1[256];
  __shared__ __align__(16) float shh[256], php[512];

  {
    int ch = tid >> 8, j = tid & 255;
    int r = offPrev + 2*n + ch;
    const float* wp = wsumP + (((size_t)p*511 + r)*4)*256;
    float w = wp[j] + wp[256+j] + wp[512+j] + wp[768+j];
    const float* ep = esumP + ((size_t)p*511 + r)*4;
    float esum = ep[0]+ep[1]+ep[2]+ep[3];
    float hatt = col[j] - w*rcpf(esum) + childH[(size_t)r*256 + j];
    if (ch) hs1[j] = hatt; else hs0[j] = hatt;
  }
  __syncthreads();
  if (tid < 256) hss[tid] = hs0[tid] + hs1[tid];
  __syncthreads();

  const float* c0 = childC + (size_t)(offPrev + 2*n)*256;
  const float* c1 = c0 + 256;
  float ai = 0.f, ao = 0.f;
  if (tid < 256){
    const uint4* wi = (const uint4*)(W16 + (size_t)tid*256);
    const uint4* wo = (const uint4*)(W16 + (size_t)(tid+256)*256);
    const float4* sv = (const float4*)hss;
    #pragma unroll 4
    for (int k = 0; k < 32; ++k){
      ai += dot8b(wi[k], sv + 2*k);
      ao += dot8b(wo[k], sv + 2*k);
    }
  } else {
    int u = tid - 256;
    const uint4* wu = (const uint4*)(W16 + (size_t)(u+512)*256);
    const uint4* wf = (const uint4*)(W16 + B16_FH + (size_t)u*256);
    const float4* sv = (const float4*)hss;
    const float4* x0 = (const float4*)hs0;
    const float4* x1 = (const float4*)hs1;
    float au = 0.f, a0 = 0.f, a1 = 0.f;
    #pragma unroll 4
    for (int k = 0; k < 32; ++k){
      au += dot8b(wu[k], sv + 2*k);
      uint4 fv = wf[k];
      a0 += dot8b(fv, x0 + 2*k);
      a1 += dot8b(fv, x1 + 2*k);
    }
    sAu[u] = au; sF0[u] = a0; sF1[u] = a1;
  }
  __syncthreads();
  if (tid < 256){
    int t = tid;
    float i_ = sigmf(ai + b_iouh[t]);
    float o_ = sigmf(ao + b_iouh[256+t]);
    float u_ = tanhfast(sAu[t] + b_iouh[512+t]);
    float bf = b_fh[t];
    float c = i_*u_ + sigmf(sF0[t]+bf)*c0[t] + sigmf(sF1[t]+bf)*c1[t];
    float h = o_*tanhfast(c);
    cmat[(size_t)(offCur+n)*256 + t] = c;
    hstage[(size_t)(offCur+n)*256 + t] = h;
    shh[t] = h;
  }
  __syncthreads();
  // hp = h_pre @ W1^T (bf16 W1, e-range split across the two thread groups)
  {
    int g = tid>>8, j = tid&255;
    const uint4* w = (const uint4*)(W16 + B16_W1 + (size_t)j*256 + g*128);
    const float4* hh = (const float4*)(shh + g*128);
    float a = 0.f;
    #pragma unroll 4
    for (int k = 0; k < 16; ++k) a += dot8b(w[k], hh + 2*k);
    php[g*256 + j] = a;
  }
  __syncthreads();
  if (tid < 256) hpbuf[(size_t)(offCur+n)*256 + tid] = php[tid] + php[256+tid];
}

// ---------------------------------------------------------------------------
// Head: finish row 510 of C and D, then MLP + log_softmax. 1 block x 256.
// ---------------------------------------------------------------------------
__global__ void __launch_bounds__(256) k_head(
    const float* __restrict__ W_wh, const float* __restrict__ b_wh,
    const float* __restrict__ W_wp, const float* __restrict__ b_wp,
    const float* __restrict__ matA, const float* __restrict__ matB,
    const float* __restrict__ colA, const float* __restrict__ colB,
    const float* __restrict__ wsumP, const float* __restrict__ esumP,
    const float* __restrict__ hstageC, const float* __restrict__ hstageD,
    float* __restrict__ out)
{
  __shared__ __align__(16) float v[512];
  __shared__ float og[128], lg[5];
  int t = threadIdx.x;
  {
    const float* wpC = wsumP + (((size_t)0*511 + 510)*4)*256;
    const float* epC = esumP + ((size_t)0*511 + 510)*4;
    float wC = wpC[t] + wpC[256+t] + wpC[512+t] + wpC[768+t];
    float eC = epC[0]+epC[1]+epC[2]+epC[3];
    float hCf = colA[t] - wC*rcpf(eC) + hstageC[(size_t)510*256 + t];
    const float* wpD = wsumP + (((size_t)1*511 + 510)*4)*256;
    const float* epD = esumP + ((size_t)1*511 + 510)*4;
    float wD = wpD[t] + wpD[256+t] + wpD[512+t] + wpD[768+t];
    float eD = epD[0]+epD[1]+epD[2]+epD[3];
    float hDf = colB[t] - wD*rcpf(eD) + hstageD[(size_t)510*256 + t];
    float lh = tanhfast(matA[(size_t)510*256 + t] + hDf);
    float rh = tanhfast(hCf + matB[(size_t)510*256 + t]);
    v[t] = lh*rh;
    v[256+t] = fabsf(lh - rh);
  }
  __syncthreads();
  if (t < 128){
    const float4* w = (const float4*)(W_wh + (size_t)t*512);
    const float4* vv = (const float4*)v;
    float a = b_wh[t];
    #pragma unroll 4
    for (int k = 0; k < 128; ++k){
      float4 wv = w[k], x = vv[k];
      a += wv.x*x.x + wv.y*x.y + wv.z*x.z + wv.w*x.w;
    }
    og[t] = sigmf(a);
  }
  __syncthreads();
  if (t < 5){
    const float* wp = W_wp + (size_t)t*128;
    float a = b_wp[t];
    for (int j = 0; j < 128; ++j) a += og[j]*wp[j];
    lg[t] = a;
  }
  __syncthreads();
  if (t == 0){
    float M = -1e30f;
    for (int c = 0; c < 5; ++c) M = fmaxf(M, lg[c]);
    float S = 0.f;
    for (int c = 0; c < 5; ++c) S += __expf(lg[c] - M);
    float L = logf(S);
    for (int c = 0; c < 5; ++c) out[c] = lg[c] - M - L;
  }
}

extern "C" void kernel_launch(void* const* d_in, const int* in_sizes, int n_in,
                              void* d_out, int out_size, void* d_ws, size_t ws_size,
                              hipStream_t stream)
{
  const int*   l_idx   = (const int*)  d_in[0];
  const int*   r_idx   = (const int*)  d_in[1];
  const float* emb     = (const float*)d_in[2];
  const float* W_ioux  = (const float*)d_in[3];
  const float* b_ioux  = (const float*)d_in[4];
  const float* W_iouh  = (const float*)d_in[5];
  const float* b_iouh  = (const float*)d_in[6];
  // d_in[7]=W_fx, d_in[8]=b_fx unused by the forward
  const float* W_fh    = (const float*)d_in[9];
  const float* b_fh    = (const float*)d_in[10];
  const float* Wa      = (const float*)d_in[11];
  const float* W_attnh = (const float*)d_in[12];
  const float* b_attnh = (const float*)d_in[13];
  const float* W_wh    = (const float*)d_in[14];
  const float* b_wh    = (const float*)d_in[15];
  const float* W_wp    = (const float*)d_in[16];
  const float* b_wp    = (const float*)d_in[17];

  float* ws = (float*)d_ws;
  float* cmatA   = ws;               float* cmatB   = cmatA + RC;
  float* cmatC   = cmatB + RC;       float* cmatD   = cmatC + RC;
  float* matA    = cmatD + RC;       float* matB    = matA + RC;
  float* hstageC = matB + RC;        float* hstageD = hstageC + RC;
  float* hpC     = hstageD + RC;     float* hpD     = hpC + RC;
  float* projA   = hpD + RC;         float* projB   = projA + RC;
  float* matTA   = projB + RC;       float* matTB   = matTA + 256*MT;
  float* colA    = matTB + 256*MT;   float* colB    = colA + 256;
  float* wsumP   = colB + 256;            // 2*511*4*256
  float* esumP   = wsumP + 2*511*4*256;   // 2*511*4
  unsigned short* W16 = (unsigned short*)(esumP + 2*511*4);  // 327,680 ushorts
  // total ~12.2 MB (<= 12.73 MB proven available in round 4)

  static const int offs[9] = {0, 256, 384, 448, 480, 496, 504, 508, 510};

  k_pack<<<128, 256, 0, stream>>>(W_iouh, W_fh, W_attnh, (unsigned*)W16);
  k_init<<<256, 768, 0, stream>>>(l_idx, r_idx, emb, W_ioux, b_ioux, b_iouh,
                                  cmatA, matA, cmatB, matB);
  for (int i = 1; i <= 8; ++i){
    int Nc = 256 >> i;
    k_levelAB<<<2*Nc, 512, 0, stream>>>(W16, b_iouh, b_fh,
                                        Nc, offs[i-1], offs[i],
                                        cmatA, matA, cmatB, matB);
  }
  k_mid<<<450, 256, 0, stream>>>(W_attnh, b_attnh, matA, matB,
                                 projA, projB, colA, colB, matTA, matTB,
                                 hpC, hpD);
  // scores for the 512 "level-0" rows of C and D (G=4)
  k_scores_t<4><<<2*(256/4)*4, 256, 0, stream>>>(hpC, hpD, projA, projB,
                                                 matTA, matTB, Wa, 256, 0,
                                                 wsumP, esumP);
  for (int i = 1; i <= 8; ++i){
    int Nc = 256 >> i;
    const float* childHC = (i == 1) ? matB  : hstageC;  // C's h0 = pass-B rows
    const float* childHD = (i == 1) ? matA  : hstageD;
    const float* childCC = (i == 1) ? cmatB : cmatC;
    const float* childCD = (i == 1) ? cmatA : cmatD;
    k_cd1<<<2*Nc, 512, 0, stream>>>(W16, b_iouh, b_fh,
                                    Nc, offs[i-1], offs[i],
                                    colA, colB, wsumP, esumP,
                                    childHC, childHD, childCC, childCD,
                                    cmatC, cmatD, hstageC, hstageD, hpC, hpD);
    if (Nc >= 4)
      k_scores_t<4><<<2*(Nc/4)*4, 256, 0, stream>>>(hpC, hpD, projA, projB,
                                                    matTA, matTB, Wa, Nc, offs[i],
                                                    wsumP, esumP);
    else if (Nc == 2)
      k_scores_t<2><<<2*(Nc/2)*4, 256, 0, stream>>>(hpC, hpD, projA, projB,
                                                    matTA, matTB, Wa, Nc, offs[i],
                                                    wsumP, esumP);
    else
      k_scores_t<1><<<2*Nc*4, 256, 0, stream>>>(hpC, hpD, projA, projB,
                                                matTA, matTB, Wa, Nc, offs[i],
                                                wsumP, esumP);
  }
  k_head<<<1, 256, 0, stream>>>(W_wh, b_wh, W_wp, b_wp, matA, matB,
                                colA, colB, wsumP, esumP, hstageC, hstageD,
                                (float*)d_out);
}

// Round 10
// 490.717 us; speedup vs baseline: 5.1997x; 1.3624x over previous
//
#include <hip/hip_runtime.h>

#define RC 130816   // 511*256
#define MT 512      // matT m-stride (511 zero-padded)

// bf16 weight cache layout (ushort offsets)
#define B16_FH   196608   // after 768*256 iou rows
#define B16_W1   262144   // 256*256 (W_attnh[:, :256])

__device__ __forceinline__ float rcpf(float x){ return __builtin_amdgcn_rcpf(x); }
__device__ __forceinline__ float sigmf(float x){ return rcpf(1.f + __expf(-x)); }
__device__ __forceinline__ float tanhfast(float x){
  return 1.f - 2.f*rcpf(1.f + __expf(2.f*x));
}

// ---- bf16-as-integer helpers ----
__device__ __forceinline__ float bfl(unsigned x){ return __uint_as_float(x << 16); }
__device__ __forceinline__ float bfh(unsigned x){ return __uint_as_float(x & 0xFFFF0000u); }
__device__ __forceinline__ unsigned bpack(float a, float b){
  unsigned ua = __float_as_uint(a), ub = __float_as_uint(b);
  return ((ua + 0x7FFFu + ((ua>>16)&1u)) >> 16)
       | ((ub + 0x7FFFu + ((ub>>16)&1u)) & 0xFFFF0000u);
}
__device__ __forceinline__ float dot8b(uint4 w, const float4* s4){
  float4 s0 = s4[0], s1 = s4[1];
  return bfl(w.x)*s0.x + bfh(w.x)*s0.y + bfl(w.y)*s0.z + bfh(w.y)*s0.w
       + bfl(w.z)*s1.x + bfh(w.z)*s1.y + bfl(w.w)*s1.z + bfh(w.w)*s1.w;
}

// ---------------------------------------------------------------------------
// Pack W_iouh / W_fh / W1 (=W_attnh[:,:256]) to bf16.
// ---------------------------------------------------------------------------
__global__ void __launch_bounds__(256) k_pack(
    const float* __restrict__ W_iouh, const float* __restrict__ W_fh,
    const float* __restrict__ W_attnh, unsigned* __restrict__ W16u)
{
  int g0 = blockIdx.x*blockDim.x + threadIdx.x, gs = gridDim.x*blockDim.x;
  for (int k = g0; k < 98304; k += gs){
    int i = 2*k; W16u[k] = bpack(W_iouh[i], W_iouh[i+1]);
  }
  for (int k = g0; k < 32768; k += gs){
    int i = 2*k; W16u[98304 + k] = bpack(W_fh[i], W_fh[i+1]);
  }
  for (int k = g0; k < 32768; k += gs){
    int i = 2*k; int t = i>>8, e = i&255;
    const float* r = W_attnh + (size_t)t*512;
    W16u[131072 + k] = bpack(r[e], r[e+1]);
  }
}

// ---------------------------------------------------------------------------
// Init: 256 blocks x 768 threads; block = (pass p, 2 rows).
// ---------------------------------------------------------------------------
__global__ void __launch_bounds__(768) k_init(
    const int* __restrict__ l_idx, const int* __restrict__ r_idx,
    const float* __restrict__ emb, const float* __restrict__ W_ioux,
    const float* __restrict__ b_ioux, const float* __restrict__ b_iouh,
    float* __restrict__ cmatA, float* __restrict__ matA,
    float* __restrict__ cmatB, float* __restrict__ matB)
{
  int b = blockIdx.x, tid = threadIdx.x;
  int p = b >> 7, n0 = (b & 127) * 2;
  __shared__ __align__(16) float xs[2*304];
  __shared__ float sg[2*768];
  for (int j = tid; j < 600; j += 768){
    int rr = j/300, d = j - rr*300;
    int row = p ? r_idx[n0+rr] : l_idx[n0+rr];
    xs[rr*304 + d] = emb[(size_t)row*300 + d];
  }
  __syncthreads();
  const float4* w = (const float4*)(W_ioux + (size_t)tid*300);
  float a0 = 0.f, a1 = 0.f;
  #pragma unroll 5
  for (int k = 0; k < 75; ++k){
    float4 wv = w[k];
    const float* x0 = xs + 4*k;
    const float* x1 = xs + 304 + 4*k;
    a0 += wv.x*x0[0] + wv.y*x0[1] + wv.z*x0[2] + wv.w*x0[3];
    a1 += wv.x*x1[0] + wv.y*x1[1] + wv.z*x1[2] + wv.w*x1[3];
  }
  float bb = b_ioux[tid] + b_iouh[tid];
  sg[tid] = a0 + bb;
  sg[768 + tid] = a1 + bb;
  __syncthreads();
  if (tid < 512){
    int rr = tid >> 8, t = tid & 255;
    const float* g = sg + rr*768;
    float c = sigmf(g[t]) * tanhfast(g[512+t]);
    float h = sigmf(g[256+t]) * tanhfast(c);
    (p ? cmatB : cmatA)[(size_t)(n0+rr)*256 + t] = c;
    (p ? matB  : matA )[(size_t)(n0+rr)*256 + t] = h;
  }
}

// ---------------------------------------------------------------------------
// A/B tree level, column-split S=4, row-batched R. 512 threads.
// blocks = (2*Nc/R)*4 : bid -> slice s (0..3), group (pass, R rows).
// Roles: 8 = gate{i,o,u,f} x d-half; LDS-combine partials.
// ---------------------------------------------------------------------------
template<int R>
__global__ void __launch_bounds__(512) k_levelAB(
    const unsigned short* __restrict__ W16, const float* __restrict__ b_iouh,
    const float* __restrict__ b_fh,
    int Nc, int offPrev, int offCur,
    float* __restrict__ cmatA, float* __restrict__ matA,
    float* __restrict__ cmatB, float* __restrict__ matB)
{
  int bid = blockIdx.x, tid = threadIdx.x;
  int s = bid & 3, g2 = bid >> 2;
  int groups = Nc / R;
  int p = (g2 >= groups) ? 1 : 0;
  int n0 = (g2 - p*groups) * R;
  float* cmat = p ? cmatB : cmatA;
  float* hmat = p ? matB  : matA;

  __shared__ __align__(16) float hs0[R][256], hs1[R][256], hss[R][256];
  __shared__ float sP[10][R][64];

  for (int it = tid; it < R*2*256; it += 512){
    int j = it & 255, ch = (it>>8)&1, r = it>>9;
    float v = hmat[(size_t)(offPrev + 2*(n0+r) + ch)*256 + j];
    if (ch) hs1[r][j] = v; else hs0[r][j] = v;
  }
  __syncthreads();
  for (int it = tid; it < R*256; it += 512){
    int j = it & 255, r = it>>8;
    hss[r][j] = hs0[r][j] + hs1[r][j];
  }
  __syncthreads();

  {
    int role = tid >> 6, cl = tid & 63;
    int gate = role & 3, dh = role >> 2;
    int col = s*64 + cl;
    if (gate < 3){
      const unsigned short* wrow = W16 + (size_t)(col + gate*256)*256;
      const uint4* w4 = (const uint4*)(wrow + dh*128);
      float acc[R];
      #pragma unroll
      for (int r = 0; r < R; ++r) acc[r] = 0.f;
      #pragma unroll 4
      for (int k = 0; k < 16; ++k){
        uint4 w = w4[k];
        #pragma unroll
        for (int r = 0; r < R; ++r)
          acc[r] += dot8b(w, (const float4*)(&hss[r][dh*128 + k*8]));
      }
      #pragma unroll
      for (int r = 0; r < R; ++r) sP[gate*2+dh][r][cl] = acc[r];
    } else {
      const uint4* w4 = (const uint4*)(W16 + B16_FH + (size_t)col*256 + dh*128);
      float a0[R], a1[R];
      #pragma unroll
      for (int r = 0; r < R; ++r){ a0[r] = 0.f; a1[r] = 0.f; }
      #pragma unroll 4
      for (int k = 0; k < 16; ++k){
        uint4 w = w4[k];
        #pragma unroll
        for (int r = 0; r < R; ++r){
          a0[r] += dot8b(w, (const float4*)(&hs0[r][dh*128 + k*8]));
          a1[r] += dot8b(w, (const float4*)(&hs1[r][dh*128 + k*8]));
        }
      }
      #pragma unroll
      for (int r = 0; r < R; ++r){ sP[6+dh][r][cl] = a0[r]; sP[8+dh][r][cl] = a1[r]; }
    }
  }
  __syncthreads();
  if (tid < 64*R){
    int r = tid >> 6, cl = tid & 63;
    int t = s*64 + cl;
    int n = n0 + r;
    float ai  = sP[0][r][cl] + sP[1][r][cl];
    float ao  = sP[2][r][cl] + sP[3][r][cl];
    float au  = sP[4][r][cl] + sP[5][r][cl];
    float af0 = sP[6][r][cl] + sP[7][r][cl];
    float af1 = sP[8][r][cl] + sP[9][r][cl];
    float c0 = cmat[(size_t)(offPrev+2*n)*256 + t];
    float c1 = cmat[(size_t)(offPrev+2*n+1)*256 + t];
    float i_ = sigmf(ai + b_iouh[t]);
    float o_ = sigmf(ao + b_iouh[256+t]);
    float u_ = tanhfast(au + b_iouh[512+t]);
    float bf = b_fh[t];
    float c = i_*u_ + sigmf(af0+bf)*c0 + sigmf(af1+bf)*c1;
    float h = o_*tanhfast(c);
    cmat[(size_t)(offCur+n)*256 + t] = c;
    hmat[(size_t)(offCur+n)*256 + t] = h;
  }
}

// ---------------------------------------------------------------------------
// Mid: proj rows (0..127), colsums (128,129), matT transposes (130..385),
// hp (php slice 0) for the 512 init rows of C/D (386..449).
// ---------------------------------------------------------------------------
__global__ void __launch_bounds__(256) k_mid(
    const float* __restrict__ W_attnh, const float* __restrict__ b_attnh,
    const float* __restrict__ matA, const float* __restrict__ matB,
    float* __restrict__ projA, float* __restrict__ projB,
    float* __restrict__ colA, float* __restrict__ colB,
    float* __restrict__ matTA, float* __restrict__ matTB,
    float* __restrict__ php)
{
  int b = blockIdx.x, tid = threadIdx.x;
  if (b < 128){
    int p = b>>6, ch = b&63, m0 = ch*8, mc = min(8, 511-m0);
    const float* mat = p ? matB : matA;
    float* proj = p ? projB : projA;
    __shared__ __align__(16) float ms[256*8];   // ms[e*8+rr]
    for (int j = tid; j < mc*256; j += 256){
      int rr = j>>8, e = j&255;
      ms[e*8+rr] = mat[(size_t)(m0+rr)*256 + e];
    }
    for (int j = tid + mc*256; j < 8*256; j += 256){
      int rr = j>>8, e = j&255; ms[e*8+rr] = 0.f;
    }
    __syncthreads();
    int t = tid;
    const float4* w2 = (const float4*)(W_attnh + (size_t)t*512 + 256);
    float acc[8] = {0,0,0,0,0,0,0,0};
    #pragma unroll 2
    for (int k = 0; k < 64; ++k){
      float4 w = w2[k];
      const float* base = ms + k*32;
      #pragma unroll
      for (int rr = 0; rr < 8; ++rr)
        acc[rr] += w.x*base[rr] + w.y*base[8+rr] + w.z*base[16+rr] + w.w*base[24+rr];
    }
    float ba = b_attnh[t];
    for (int rr = 0; rr < mc; ++rr) proj[(size_t)(m0+rr)*256 + t] = acc[rr] + ba;
  } else if (b < 130){
    int p = b - 128;
    const float* mat = p ? matB : matA;
    float* col = p ? colB : colA;
    float s = 0.f;
    #pragma unroll 8
    for (int m = 0; m < 511; ++m) s += mat[(size_t)m*256 + tid];
    col[tid] = s;
  } else if (b < 386){
    int idx = b - 130;
    int p = idx>>7, rem = idx&127, jt = rem>>4, mt = rem&15;
    const float* mat = p ? matB : matA;
    float* matT = p ? matTB : matTA;
    __shared__ float tile[32][33];
    int c = tid&31, r0 = tid>>5;
    int m0 = mt*32, j0 = jt*32;
    #pragma unroll
    for (int k = 0; k < 4; ++k){
      int m = m0 + r0 + 8*k;
      tile[r0+8*k][c] = (m < 511) ? mat[(size_t)m*256 + j0 + c] : 0.f;
    }
    __syncthreads();
    #pragma unroll
    for (int k = 0; k < 4; ++k){
      int jj = r0 + 8*k;
      matT[(size_t)(j0+jj)*MT + m0 + c] = tile[c][jj];
    }
  } else {
    int idx = b - 386;           // 64 blocks: p (C/D) x 32 chunks of 8 rows
    int p = idx>>5, ch = idx&31, r0 = ch*8;
    const float* hsrc = p ? matA : matB;   // C<-B, D<-A
    __shared__ __align__(16) float ms[256*8];
    for (int j = tid; j < 8*256; j += 256){
      int rr = j>>8, e = j&255;
      ms[e*8+rr] = hsrc[(size_t)(r0+rr)*256 + e];
    }
    __syncthreads();
    int t = tid;
    const float4* w1 = (const float4*)(W_attnh + (size_t)t*512);
    float acc[8] = {0,0,0,0,0,0,0,0};
    #pragma unroll 2
    for (int k = 0; k < 64; ++k){
      float4 w = w1[k];
      const float* base = ms + k*32;
      #pragma unroll
      for (int rr = 0; rr < 8; ++rr)
        acc[rr] += w.x*base[rr] + w.y*base[8+rr] + w.z*base[16+rr] + w.w*base[24+rr];
    }
    #pragma unroll
    for (int rr = 0; rr < 8; ++rr)
      php[(((size_t)p*511 + r0+rr)*4 + 0)*256 + t] = acc[rr];
  }
}

// ---------------------------------------------------------------------------
// Tiled scores: block = (pass, G-row group, m-chunk of 128). hp = sum of S
// php slices per row. Writes unnormalized wsumP + esumP.
// ---------------------------------------------------------------------------
template<int G>
__global__ void __launch_bounds__(256) k_scores_t(
    const float* __restrict__ php,
    const float* __restrict__ projA, const float* __restrict__ projB,
    const float* __restrict__ matTA, const float* __restrict__ matTB,
    const float* __restrict__ Wa, int Nc, int rowOff, int S,
    float* __restrict__ wsumP, float* __restrict__ esumP)
{
  int b = blockIdx.x, tid = threadIdx.x;
  int groups = Nc / G;
  int per = groups * 4;
  int p = b / per; int rem = b - p*per; int g = rem >> 2, ch = rem & 3;
  int row0 = rowOff + g*G;
  const float* proj = p ? projB : projA;
  const float* matT = p ? matTB : matTA;

  __shared__ __align__(16) float shp[G*256];
  __shared__ __align__(16) float swa[256];
  __shared__ __align__(16) float spart[G*256];
  __shared__ __align__(16) float se[G*128];

  for (int j = tid; j < G*256; j += 256){
    int row = row0 + (j>>8), jj = j&255;
    const float* base = php + (((size_t)p*511 + row)*4)*256 + jj;
    float v = base[0];
    if (S == 4) v += base[256] + base[512] + base[768];
    shp[j] = v;
  }
  swa[tid] = Wa[tid];
  __syncthreads();

  int ml = tid & 127, dh = tid >> 7;
  int m = ch*128 + ml;
  float part[G];
  #pragma unroll
  for (int r = 0; r < G; ++r) part[r] = 0.f;
  if (m < 511){
    const float4* pr  = (const float4*)(proj + (size_t)m*256 + dh*128);
    const float4* wa4 = (const float4*)(swa + dh*128);
    #pragma unroll 4
    for (int k = 0; k < 32; ++k){
      float4 pv = pr[k], wv = wa4[k];
      int dbase = dh*128 + k*4;
      #pragma unroll
      for (int r = 0; r < G; ++r){
        const float* hr = shp + r*256 + dbase;
        part[r] += wv.x*tanhfast(hr[0]+pv.x) + wv.y*tanhfast(hr[1]+pv.y)
                 + wv.z*tanhfast(hr[2]+pv.z) + wv.w*tanhfast(hr[3]+pv.w);
      }
    }
  }
  #pragma unroll
  for (int r = 0; r < G; ++r) spart[r*256 + tid] = part[r];
  __syncthreads();
  if (tid < 128){
    #pragma unroll
    for (int r = 0; r < G; ++r){
      float s = spart[r*256 + ml] + spart[r*256 + 128 + ml];
      se[r*128 + ml] = (ch*128 + ml < 511) ? __expf(s) : 0.f;
    }
  }
  __syncthreads();
  {
    const float4* mt = (const float4*)(matT + (size_t)tid*MT + ch*128);
    float acc[G];
    #pragma unroll
    for (int r = 0; r < G; ++r) acc[r] = 0.f;
    #pragma unroll 4
    for (int k = 0; k < 32; ++k){
      float4 mv = mt[k];
      #pragma unroll
      for (int r = 0; r < G; ++r){
        float4 ev = ((const float4*)(se + r*128))[k];
        acc[r] += mv.x*ev.x + mv.y*ev.y + mv.z*ev.z + mv.w*ev.w;
      }
    }
    #pragma unroll
    for (int r = 0; r < G; ++r)
      wsumP[(((size_t)p*511 + row0 + r)*4 + ch)*256 + tid] = acc[r];
  }
  if (tid < G){
    float s = 0.f;
    const float* sr = se + tid*128;
    for (int k = 0; k < 128; ++k) s += sr[k];
    esumP[((size_t)p*511 + row0 + tid)*4 + ch] = s;
  }
}

// ---------------------------------------------------------------------------
// CD spine, column-split S=4, row-batched R. 512 threads.
// Phase1: attend-finish children (full width). Phase2: gate dots (own cols).
// Phase3: c,h finalize (own cols). Phase4: hp partial slice -> php.
// ---------------------------------------------------------------------------
template<int R>
__global__ void __launch_bounds__(512) k_cd1(
    const unsigned short* __restrict__ W16, const float* __restrict__ b_iouh,
    const float* __restrict__ b_fh,
    int Nc, int offPrev, int offCur,
    const float* __restrict__ colA, const float* __restrict__ colB,
    const float* __restrict__ wsumP, const float* __restrict__ esumP,
    const float* __restrict__ childHC, const float* __restrict__ childHD,
    const float* __restrict__ childCC, const float* __restrict__ childCD_,
    float* __restrict__ cmatC, float* __restrict__ cmatD,
    float* __restrict__ hstageC, float* __restrict__ hstageD,
    float* __restrict__ php)
{
  int bid = blockIdx.x, tid = threadIdx.x;
  int s = bid & 3, g2 = bid >> 2;
  int groups = Nc / R;
  int p = (g2 >= groups) ? 1 : 0;
  int n0 = (g2 - p*groups) * R;
  const float* colv   = p ? colB : colA;
  const float* childH = p ? childHD : childHC;
  const float* childC = p ? childCD_ : childCC;
  float* cmat   = p ? cmatD : cmatC;
  float* hstage = p ? hstageD : hstageC;

  __shared__ __align__(16) float hs0[R][256], hs1[R][256], hss[R][256];
  __shared__ float sP[10][R][64];
  __shared__ __align__(16) float sh[R][64];
  __shared__ float sHP[2][256];

  // Phase 1: attend-finish both children of each of the R rows (full width)
  for (int it = tid; it < R*2*256; it += 512){
    int j = it & 255, ch = (it>>8)&1, r = it>>9;
    int rc = offPrev + 2*(n0+r) + ch;
    const float* wp = wsumP + (((size_t)p*511 + rc)*4)*256;
    const float* ep = esumP + ((size_t)p*511 + rc)*4;
    float w = wp[j] + wp[256+j] + wp[512+j] + wp[768+j];
    float esum = ep[0]+ep[1]+ep[2]+ep[3];
    float hatt = colv[j] - w*rcpf(esum) + childH[(size_t)rc*256 + j];
    if (ch) hs1[r][j] = hatt; else hs0[r][j] = hatt;
  }
  __syncthreads();
  for (int it = tid; it < R*256; it += 512){
    int j = it & 255, r = it>>8;
    hss[r][j] = hs0[r][j] + hs1[r][j];
  }
  __syncthreads();

  // Phase 2: gate dots for own 64 columns
  {
    int role = tid >> 6, cl = tid & 63;
    int gate = role & 3, dh = role >> 2;
    int col = s*64 + cl;
    if (gate < 3){
      const unsigned short* wrow = W16 + (size_t)(col + gate*256)*256;
      const uint4* w4 = (const uint4*)(wrow + dh*128);
      float acc[R];
      #pragma unroll
      for (int r = 0; r < R; ++r) acc[r] = 0.f;
      #pragma unroll 4
      for (int k = 0; k < 16; ++k){
        uint4 w = w4[k];
        #pragma unroll
        for (int r = 0; r < R; ++r)
          acc[r] += dot8b(w, (const float4*)(&hss[r][dh*128 + k*8]));
      }
      #pragma unroll
      for (int r = 0; r < R; ++r) sP[gate*2+dh][r][cl] = acc[r];
    } else {
      const uint4* w4 = (const uint4*)(W16 + B16_FH + (size_t)col*256 + dh*128);
      float a0[R], a1[R];
      #pragma unroll
      for (int r = 0; r < R; ++r){ a0[r] = 0.f; a1[r] = 0.f; }
      #pragma unroll 4
      for (int k = 0; k < 16; ++k){
        uint4 w = w4[k];
        #pragma unroll
        for (int r = 0; r < R; ++r){
          a0[r] += dot8b(w, (const float4*)(&hs0[r][dh*128 + k*8]));
          a1[r] += dot8b(w, (const float4*)(&hs1[r][dh*128 + k*8]));
        }
      }
      #pragma unroll
      for (int r = 0; r < R; ++r){ sP[6+dh][r][cl] = a0[r]; sP[8+dh][r][cl] = a1[r]; }
    }
  }
  __syncthreads();

  // Phase 3: finalize c,h for own columns
  if (tid < 64*R){
    int r = tid >> 6, cl = tid & 63;
    int t = s*64 + cl;
    int n = n0 + r;
    float ai  = sP[0][r][cl] + sP[1][r][cl];
    float ao  = sP[2][r][cl] + sP[3][r][cl];
    float au  = sP[4][r][cl] + sP[5][r][cl];
    float af0 = sP[6][r][cl] + sP[7][r][cl];
    float af1 = sP[8][r][cl] + sP[9][r][cl];
    float c0 = childC[(size_t)(offPrev+2*n)*256 + t];
    float c1 = childC[(size_t)(offPrev+2*n+1)*256 + t];
    float i_ = sigmf(ai + b_iouh[t]);
    float o_ = sigmf(ao + b_iouh[256+t]);
    float u_ = tanhfast(au + b_iouh[512+t]);
    float bf = b_fh[t];
    float c = i_*u_ + sigmf(af0+bf)*c0 + sigmf(af1+bf)*c1;
    float h = o_*tanhfast(c);
    cmat[(size_t)(offCur+n)*256 + t] = c;
    hstage[(size_t)(offCur+n)*256 + t] = h;
    sh[r][cl] = h;
  }
  __syncthreads();

  // Phase 4: hp partial over own e-slice -> php[p][row][s][:]
  {
    int j = tid & 255, eh = tid >> 8;
    const uint4* w1 = (const uint4*)(W16 + B16_W1 + (size_t)j*256 + s*64 + eh*32);
    uint4 wv[4];
    #pragma unroll
    for (int k = 0; k < 4; ++k) wv[k] = w1[k];
    float aacc[R];
    #pragma unroll
    for (int r = 0; r < R; ++r){
      float a = 0.f;
      #pragma unroll
      for (int k = 0; k < 4; ++k)
        a += dot8b(wv[k], (const float4*)(&sh[r][eh*32 + k*8]));
      aacc[r] = a;
    }
    #pragma unroll
    for (int r = 0; r < R; ++r){
      sHP[eh][j] = aacc[r];
      __syncthreads();
      if (tid < 256){
        int row = offCur + n0 + r;
        php[(((size_t)p*511 + row)*4 + s)*256 + tid] = sHP[0][tid] + sHP[1][tid];
      }
      __syncthreads();
    }
  }
}

// ---------------------------------------------------------------------------
// Head: finish row 510 of C and D, then MLP + log_softmax. 1 block x 256.
// ---------------------------------------------------------------------------
__global__ void __launch_bounds__(256) k_head(
    const float* __restrict__ W_wh, const float* __restrict__ b_wh,
    const float* __restrict__ W_wp, const float* __restrict__ b_wp,
    const float* __restrict__ matA, const float* __restrict__ matB,
    const float* __restrict__ colA, const float* __restrict__ colB,
    const float* __restrict__ wsumP, const float* __restrict__ esumP,
    const float* __restrict__ hstageC, const float* __restrict__ hstageD,
    float* __restrict__ out)
{
  __shared__ __align__(16) float v[512];
  __shared__ float og[128], lg[5];
  int t = threadIdx.x;
  {
    const float* wpC = wsumP + (((size_t)0*511 + 510)*4)*256;
    const float* epC = esumP + ((size_t)0*511 + 510)*4;
    float wC = wpC[t] + wpC[256+t] + wpC[512+t] + wpC[768+t];
    float eC = epC[0]+epC[1]+epC[2]+epC[3];
    float hCf = colA[t] - wC*rcpf(eC) + hstageC[(size_t)510*256 + t];
    const float* wpD = wsumP + (((size_t)1*511 + 510)*4)*256;
    const float* epD = esumP + ((size_t)1*511 + 510)*4;
    float wD = wpD[t] + wpD[256+t] + wpD[512+t] + wpD[768+t];
    float eD = epD[0]+epD[1]+epD[2]+epD[3];
    float hDf = colB[t] - wD*rcpf(eD) + hstageD[(size_t)510*256 + t];
    float lh = tanhfast(matA[(size_t)510*256 + t] + hDf);
    float rh = tanhfast(hCf + matB[(size_t)510*256 + t]);
    v[t] = lh*rh;
    v[256+t] = fabsf(lh - rh);
  }
  __syncthreads();
  if (t < 128){
    const float4* w = (const float4*)(W_wh + (size_t)t*512);
    const float4* vv = (const float4*)v;
    float a = b_wh[t];
    #pragma unroll 4
    for (int k = 0; k < 128; ++k){
      float4 wv = w[k], x = vv[k];
      a += wv.x*x.x + wv.y*x.y + wv.z*x.z + wv.w*x.w;
    }
    og[t] = sigmf(a);
  }
  __syncthreads();
  if (t < 5){
    const float* wp = W_wp + (size_t)t*128;
    float a = b_wp[t];
    for (int j = 0; j < 128; ++j) a += og[j]*wp[j];
    lg[t] = a;
  }
  __syncthreads();
  if (t == 0){
    float M = -1e30f;
    for (int c = 0; c < 5; ++c) M = fmaxf(M, lg[c]);
    float S = 0.f;
    for (int c = 0; c < 5; ++c) S += __expf(lg[c] - M);
    float L = logf(S);
    for (int c = 0; c < 5; ++c) out[c] = lg[c] - M - L;
  }
}

extern "C" void kernel_launch(void* const* d_in, const int* in_sizes, int n_in,
                              void* d_out, int out_size, void* d_ws, size_t ws_size,
                              hipStream_t stream)
{
  const int*   l_idx   = (const int*)  d_in[0];
  const int*   r_idx   = (const int*)  d_in[1];
  const float* emb     = (const float*)d_in[2];
  const float* W_ioux  = (const float*)d_in[3];
  const float* b_ioux  = (const float*)d_in[4];
  const float* W_iouh  = (const float*)d_in[5];
  const float* b_iouh  = (const float*)d_in[6];
  // d_in[7]=W_fx, d_in[8]=b_fx unused by the forward
  const float* W_fh    = (const float*)d_in[9];
  const float* b_fh    = (const float*)d_in[10];
  const float* Wa      = (const float*)d_in[11];
  const float* W_attnh = (const float*)d_in[12];
  const float* b_attnh = (const float*)d_in[13];
  const float* W_wh    = (const float*)d_in[14];
  const float* b_wh    = (const float*)d_in[15];
  const float* W_wp    = (const float*)d_in[16];
  const float* b_wp    = (const float*)d_in[17];

  float* ws = (float*)d_ws;
  float* cmatA   = ws;               float* cmatB   = cmatA + RC;
  float* cmatC   = cmatB + RC;       float* cmatD   = cmatC + RC;
  float* matA    = cmatD + RC;       float* matB    = matA + RC;
  float* hstageC = matB + RC;        float* hstageD = hstageC + RC;
  float* projA   = hstageD + RC;     float* projB   = projA + RC;
  float* matTA   = projB + RC;       float* matTB   = matTA + 256*MT;
  float* colA    = matTB + 256*MT;   float* colB    = colA + 256;
  float* wsumP   = colB + 256;            // 2*511*4*256
  float* esumP   = wsumP + 2*511*4*256;   // 2*511*4
  float* php     = esumP + 2*511*4;       // 2*511*4*256
  unsigned short* W16 = (unsigned short*)(php + 2*511*4*256);  // 327,680 ushorts
  // total ~15.4 MB (ws is ~268 MB)

  static const int offs[9] = {0, 256, 384, 448, 480, 496, 504, 508, 510};

  k_pack<<<128, 256, 0, stream>>>(W_iouh, W_fh, W_attnh, (unsigned*)W16);
  k_init<<<256, 768, 0, stream>>>(l_idx, r_idx, emb, W_ioux, b_ioux, b_iouh,
                                  cmatA, matA, cmatB, matB);
  for (int i = 1; i <= 8; ++i){
    int Nc = 256 >> i;
    int oP = offs[i-1], oC = offs[i];
    if (Nc >= 128)
      k_levelAB<4><<<(2*Nc/4)*4, 512, 0, stream>>>(W16, b_iouh, b_fh, Nc, oP, oC,
                                                   cmatA, matA, cmatB, matB);
    else if (Nc >= 64)
      k_levelAB<2><<<(2*Nc/2)*4, 512, 0, stream>>>(W16, b_iouh, b_fh, Nc, oP, oC,
                                                   cmatA, matA, cmatB, matB);
    else
      k_levelAB<1><<<(2*Nc)*4, 512, 0, stream>>>(W16, b_iouh, b_fh, Nc, oP, oC,
                                                 cmatA, matA, cmatB, matB);
  }
  k_mid<<<450, 256, 0, stream>>>(W_attnh, b_attnh, matA, matB,
                                 projA, projB, colA, colB, matTA, matTB, php);
  // scores for the 512 "level-0" rows of C and D (G=4, S=1)
  k_scores_t<4><<<2*(256/4)*4, 256, 0, stream>>>(php, projA, projB,
                                                 matTA, matTB, Wa, 256, 0, 1,
                                                 wsumP, esumP);
  for (int i = 1; i <= 8; ++i){
    int Nc = 256 >> i;
    int oP = offs[i-1], oC = offs[i];
    const float* childHC = (i == 1) ? matB  : hstageC;  // C's h0 = pass-B rows
    const float* childHD = (i == 1) ? matA  : hstageD;
    const float* childCC = (i == 1) ? cmatB : cmatC;
    const float* childCD = (i == 1) ? cmatA : cmatD;
    if (Nc >= 128)
      k_cd1<4><<<(2*Nc/4)*4, 512, 0, stream>>>(W16, b_iouh, b_fh, Nc, oP, oC,
                                               colA, colB, wsumP, esumP,
                                               childHC, childHD, childCC, childCD,
                                               cmatC, cmatD, hstageC, hstageD, php);
    else if (Nc >= 64)
      k_cd1<2><<<(2*Nc/2)*4, 512, 0, stream>>>(W16, b_iouh, b_fh, Nc, oP, oC,
                                               colA, colB, wsumP, esumP,
                                               childHC, childHD, childCC, childCD,
                                               cmatC, cmatD, hstageC, hstageD, php);
    else
      k_cd1<1><<<(2*Nc)*4, 512, 0, stream>>>(W16, b_iouh, b_fh, Nc, oP, oC,
                                             colA, colB, wsumP, esumP,
                                             childHC, childHD, childCC, childCD,
                                             cmatC, cmatD, hstageC, hstageD, php);
    if (Nc >= 4)
      k_scores_t<4><<<2*(Nc/4)*4, 256, 0, stream>>>(php, projA, projB,
                                                    matTA, matTB, Wa, Nc, offs[i], 4,
                                                    wsumP, esumP);
    else if (Nc == 2)
      k_scores_t<2><<<2*(Nc/2)*4, 256, 0, stream>>>(php, projA, projB,
                                                    matTA, matTB, Wa, Nc, offs[i], 4,
                                                    wsumP, esumP);
    else
      k_scores_t<1><<<2*Nc*4, 256, 0, stream>>>(php, projA, projB,
                                                matTA, matTB, Wa, Nc, offs[i], 4,
                                                wsumP, esumP);
  }
  k_head<<<1, 256, 0, stream>>>(W_wh, b_wh, W_wp, b_wp, matA, matB,
                                colA, colB, wsumP, esumP, hstageC, hstageD,
                                (float*)d_out);
}